// Round 10
// baseline (306.724 us; speedup 1.0000x reference)
//
#include <hip/hip_runtime.h>
#include <math.h>

// SuperVoxel critical-component loss on MI355X.
// mean( (0.5 + 0.25*neg + 0.25*pos) * bce_loss )
// Run-based two-level CCL with path-halving union-find and PER-RUN loss sums.
//  k_maskloss: read floats ONCE -> fg masks, run starts/prefixes/counts,
//              per-run loss sums (wave-private LDS atomics), 0.5*sum(loss).
//  k_strip:    32-row strips, intra-strip unions+flags in 64KB LDS,
//              used-slots-only, path-halving finds.
//  k_bound:    global flag-carrying unions on 31 strip seams per image.
//  k_accumrun: per used run slot: root flag ? 0.25*runsum : 0 -> partials.

#define HH 1024
#define WW 1024
#define IMGPIX (HH * WW)
#define NB_TOTAL 16
#define FLAGBIT 0x40000000
#define IDXMASK 0x3FFFFFFF
#define NBLK 2048
#define NPART 2048
#define NTHR 256
#define WPR 16               // u64 mask words per row
#define RPR 512              // run slots per row (hard worst case)
#define SROWS 32             // rows per strip
#define STRIPS (HH / SROWS)  // 32 strips per image
#define SLOTS (SROWS * RPR)  // 16384 slots per strip (64KB LDS)
#define NTHR_S 1024

typedef unsigned long long u64;

// ---------- global union-find, path-halving, flag-aware ----------
__device__ __forceinline__ int findRootH(int* p, int i) {
    volatile int* vp = p;
    int r = i;
    int e = vp[r] & IDXMASK;
    while (e != r) {
        int e2 = vp[e] & IDXMASK;
        if (e2 != e) p[r] = e2;  // shortcut: only non-roots written (no flags there)
        r = e; e = e2;
    }
    return r;
}

__device__ __forceinline__ void flagProp(int* p, int x) {
    while (true) {
        int r = findRootH(p, x);
        int old = atomicOr(&p[r], FLAGBIT);
        if ((old & IDXMASK) == r) return;  // was still a root
        x = old & IDXMASK;
    }
}

__device__ __forceinline__ void uniteGF(int* p, int a, int b) {
    int ra = findRootH(p, a), rb = findRootH(p, b);
    while (ra != rb) {
        if (ra < rb) { int t = ra; ra = rb; rb = t; }  // hook larger under smaller
        int e = p[ra];
        if ((e & IDXMASK) != ra) { ra = findRootH(p, e & IDXMASK); continue; }
        int prev = atomicCAS(&p[ra], e, rb);
        if (prev == e) {
            if (e & FLAGBIT) flagProp(p, rb);
            return;
        }
        ra = findRootH(p, prev & IDXMASK);
        rb = findRootH(p, rb);
    }
}

// ---------- LDS union-find, path-halving ----------
__device__ __forceinline__ int findRootL(int* lab, int i) {
    volatile int* vl = lab;
    int r = i;
    int e = vl[r] & IDXMASK;
    while (e != r) {
        int e2 = vl[e] & IDXMASK;
        if (e2 != e) lab[r] = e2;
        r = e; e = e2;
    }
    return r;
}

__device__ __forceinline__ void uniteL(int* lab, int a, int b) {
    int ra = findRootL(lab, a), rb = findRootL(lab, b);
    while (ra != rb) {
        if (ra < rb) { int t = ra; ra = rb; rb = t; }
        int prev = atomicCAS(&lab[ra], ra, rb);
        if (prev == ra) return;
        ra = findRootL(lab, prev & IDXMASK);
        rb = findRootL(lab, rb);
    }
}

// index (within row) of the run containing bit b of this word; requires fg@b.
__device__ __forceinline__ int runIndexW(u64 starts, int b) {
    u64 below = (2ULL << b) - 1ULL;  // b=63 wraps to ~0ULL
    return (int)__popcll(starts & below) - 1;
}

__global__ void k_zero(double* __restrict__ part) {
    part[blockIdx.x * blockDim.x + threadIdx.x] = 0.0;
}

// Wave-per-row: read floats once; per-run LDS loss sums; lane-parallel masks.
__global__ void k_maskloss(const float* __restrict__ preds, const float* __restrict__ targets,
                           long gbase, int nrows,
                           u64* __restrict__ fT, u64* __restrict__ fP,
                           u64* __restrict__ sT, u64* __restrict__ sP,
                           int* __restrict__ prT, int* __restrict__ prP,
                           int* __restrict__ rcT, int* __restrict__ rcP,
                           float* __restrict__ runsumT, float* __restrict__ runsumP,
                           double* __restrict__ part) {
    __shared__ float rsT[4][RPR];
    __shared__ float rsP[4][RPR];
    __shared__ double sh[4];
    int wid = threadIdx.x >> 6, lane = threadIdx.x & 63;
    double lsum = 0.0;
    for (int rbase = blockIdx.x * 4; rbase < nrows; rbase += gridDim.x * 4) {
        int R = rbase + wid;  // nrows is a multiple of 4 -> R always valid
        long pixbase = (long)R * WW;
        for (int k = lane; k < RPR; k += 64) { rsT[wid][k] = 0.0f; rsP[wid][k] = 0.0f; }
        __syncthreads();
        u64 myW = 0;  // lanes 0..15: T word[lane]; lanes 16..31: P word[lane-16]
        int cumT = 0, cumP = 0;
        u64 carryT = 0, carryP = 0;
        #pragma unroll 4
        for (int w = 0; w < WPR; ++w) {
            long g = gbase + pixbase + w * 64 + lane;
            float p = preds[g], t = targets[g];
            float loss = fmaxf(p, 0.0f) - p * t + __logf(1.0f + __expf(-fabsf(p)));
            lsum += (double)loss;
            bool tf = t > 0.0f, pf = p > 0.5f;
            u64 bt = __ballot(tf);
            u64 bp = __ballot(pf);
            u64 stT = bt & ~((bt << 1) | carryT);
            u64 stP = bp & ~((bp << 1) | carryP);
            if (tf) atomicAdd(&rsT[wid][cumT + runIndexW(stT, lane)], loss);
            if (pf) atomicAdd(&rsP[wid][cumP + runIndexW(stP, lane)], loss);
            cumT += (int)__popcll(stT); carryT = bt >> 63;
            cumP += (int)__popcll(stP); carryP = bp >> 63;
            if (lane == w) myW = bt;
            if (lane == w + 16) myW = bp;
        }
        // masks / starts / prefixes via lane-parallel shfl scan (lanes < 32)
        if (lane < 32) {
            int subid = lane & 15;
            u64 prevW = __shfl_up(myW, 1, 16);
            u64 carry = (subid > 0) ? (prevW >> 63) : 0ULL;
            u64 st = myW & ~((myW << 1) | carry);
            int cnt = (int)__popcll(st);
            int incl = cnt;
            #pragma unroll
            for (int d = 1; d < 16; d <<= 1) {
                int v = __shfl_up(incl, d, 16);
                if (subid >= d) incl += v;
            }
            int excl = incl - cnt;
            int wi = R * WPR + subid;
            if (lane < 16) {
                fT[wi] = myW; sT[wi] = st; prT[wi] = excl;
                if (subid == 15) rcT[R] = incl;
            } else {
                fP[wi] = myW; sP[wi] = st; prP[wi] = excl;
                if (subid == 15) rcP[R] = incl;
            }
        }
        __syncthreads();
        // copy out used run sums (coalesced)
        for (int k = lane; k < cumT; k += 64) runsumT[(long)R * RPR + k] = rsT[wid][k];
        for (int k = lane; k < cumP; k += 64) runsumP[(long)R * RPR + k] = rsP[wid][k];
        __syncthreads();
    }
    lsum *= 0.5;
    #pragma unroll
    for (int off = 32; off > 0; off >>= 1) lsum += __shfl_down(lsum, off, 64);
    if (lane == 0) sh[wid] = lsum;
    __syncthreads();
    if (threadIdx.x == 0) part[blockIdx.x] += sh[0] + sh[1] + sh[2] + sh[3];
}

// One block per (image, strip, phase): intra-strip CCL + flags in 64KB LDS.
__global__ __launch_bounds__(NTHR_S) void
k_strip(const u64* __restrict__ fT, const u64* __restrict__ fP,
        const u64* __restrict__ sT, const u64* __restrict__ sP,
        const int* __restrict__ prT, const int* __restrict__ prP,
        const int* __restrict__ rcT, const int* __restrict__ rcP,
        int* __restrict__ parentT, int* __restrict__ parentP) {
    __shared__ int lab[SLOTS];
    __shared__ int rcL[SROWS];
    int bid = blockIdx.x;
    int ph = bid & 1; bid >>= 1;
    int strip = bid & (STRIPS - 1);
    int img = bid >> 5;  // STRIPS = 32
    const u64* f = ph ? fP : fT;
    const u64* fB = ph ? fT : fP;
    const u64* s = ph ? sP : sT;
    const int* pr = ph ? prP : prT;
    const int* rc = ph ? rcP : rcT;
    int* parent = ph ? parentP : parentT;
    const int row0 = img * HH + strip * SROWS;

    if (threadIdx.x < SROWS) rcL[threadIdx.x] = rc[row0 + threadIdx.x];
    __syncthreads();

    // init used slots only
    for (int i = threadIdx.x; i < SLOTS; i += NTHR_S)
        if ((i & (RPR - 1)) < rcL[i >> 9]) lab[i] = i;
    __syncthreads();

    // intra-strip vertical unites, 2-way sub-word split
    for (int task = threadIdx.x; task < (SROWS - 1) * WPR * 2; task += NTHR_S) {
        int j = task & 1, w = (task >> 1) & 15, r = task >> 5;
        int w0 = (row0 + r) * WPR + w, w1 = w0 + WPR;
        u64 o = f[w0] & f[w1];
        if (!o) continue;
        u64 s0 = s[w0], s1 = s[w1];
        int b0 = r * RPR + pr[w0], b1 = (r + 1) * RPR + pr[w1];
        u64 os = o & ~(o << 1);
        int k = 0;
        while (os) {
            int b = __builtin_ctzll(os);
            os &= os - 1;
            if ((k++ & 1) == j)
                uniteL(lab, b0 + runIndexW(s0, b), b1 + runIndexW(s1, b));
        }
    }
    __syncthreads();

    // mistake flags onto local roots, 2-way sub-word split
    for (int task = threadIdx.x; task < SROWS * WPR * 2; task += NTHR_S) {
        int j = task & 1, w = (task >> 1) & 15, r = task >> 5;
        int wi = (row0 + r) * WPR + w;
        u64 m = f[wi] & ~fB[wi];
        if (!m) continue;
        u64 sw = s[wi];
        int base = r * RPR + pr[wi];
        u64 ms = m & ~(m << 1);
        int k = 0, last = -1;
        while (ms) {
            int b = __builtin_ctzll(ms);
            ms &= ms - 1;
            if ((k++ & 1) != j) continue;
            int rid = base + runIndexW(sw, b);
            if (rid == last) continue;
            last = rid;
            int rt = findRootL(lab, rid);
            if (!(((volatile int*)lab)[rt] & FLAGBIT)) atomicOr(&lab[rt], FLAGBIT);
        }
    }
    __syncthreads();

    // compress + write used slots (root entries carry flag)
    const int gb = row0 * RPR;
    for (int i = threadIdx.x; i < SLOTS; i += NTHR_S) {
        if ((i & (RPR - 1)) >= rcL[i >> 9]) continue;
        int e = lab[i];
        int rt = e & IDXMASK;
        if (rt != i) rt = findRootL(lab, rt);
        parent[gb + i] = (rt == i) ? ((gb + i) | (e & FLAGBIT)) : (gb + rt);
    }
}

// Global flag-carrying unions across the 31 strip seams per image.
__global__ void k_bound(const u64* __restrict__ fT, const u64* __restrict__ fP,
                        const u64* __restrict__ sT, const u64* __restrict__ sP,
                        const int* __restrict__ prT, const int* __restrict__ prP,
                        int* __restrict__ parentT, int* __restrict__ parentP, int nb) {
    int tasks = nb * (STRIPS - 1) * WPR * 2;
    int stride = gridDim.x * blockDim.x;
    for (int id = blockIdx.x * blockDim.x + threadIdx.x; id < tasks; id += stride) {
        int ph = id & 1;
        int t = id >> 1;
        int w = t & 15; t >>= 4;
        int bnd = t % (STRIPS - 1);
        int img = t / (STRIPS - 1);
        int R = img * HH + bnd * SROWS + (SROWS - 1);  // last row of strip bnd
        const u64* f = ph ? fP : fT;
        const u64* s = ph ? sP : sT;
        const int* pr = ph ? prP : prT;
        int* parent = ph ? parentP : parentT;
        int w0 = R * WPR + w, w1 = w0 + WPR;
        u64 o = f[w0] & f[w1];
        if (!o) continue;
        u64 s0 = s[w0], s1 = s[w1];
        int b0 = R * RPR + pr[w0], b1 = (R + 1) * RPR + pr[w1];
        u64 os = o & ~(o << 1);
        while (os) {
            int b = __builtin_ctzll(os);
            os &= os - 1;
            uniteGF(parent, b0 + runIndexW(s0, b), b1 + runIndexW(s1, b));
        }
    }
}

// Per used run slot: if final root flagged, add 0.25*runsum. -> partials.
__global__ void k_accumrun(const int* __restrict__ rcT, const int* __restrict__ rcP,
                           int* __restrict__ parentT, int* __restrict__ parentP,
                           const float* __restrict__ runsumT, const float* __restrict__ runsumP,
                           double* __restrict__ part, int nslots) {
    int stride = gridDim.x * blockDim.x;
    double local = 0.0;
    for (int i = blockIdx.x * blockDim.x + threadIdx.x; i < nslots; i += stride) {
        int row = i >> 9, k = i & (RPR - 1);
        if (k < rcT[row]) {
            int e = parentT[i];
            int r = e & IDXMASK;
            int fl;
            if (r == i) fl = e & FLAGBIT;
            else { r = findRootH(parentT, r); fl = parentT[r] & FLAGBIT; }
            if (fl) local += 0.25 * (double)runsumT[i];
        }
        if (k < rcP[row]) {
            int e = parentP[i];
            int r = e & IDXMASK;
            int fl;
            if (r == i) fl = e & FLAGBIT;
            else { r = findRootH(parentP, r); fl = parentP[r] & FLAGBIT; }
            if (fl) local += 0.25 * (double)runsumP[i];
        }
    }
    #pragma unroll
    for (int off = 32; off > 0; off >>= 1) local += __shfl_down(local, off, 64);
    __shared__ double sh[NTHR / 64];
    int lane = threadIdx.x & 63, wid = threadIdx.x >> 6;
    if (lane == 0) sh[wid] = local;
    __syncthreads();
    if (threadIdx.x == 0) {
        double tot = 0.0;
        #pragma unroll
        for (int w = 0; w < NTHR / 64; ++w) tot += sh[w];
        part[blockIdx.x] += tot;
    }
}

__global__ void k_final(const double* __restrict__ part, float* __restrict__ out, double inv_n) {
    double v = 0.0;
    for (int i = threadIdx.x; i < NPART; i += blockDim.x) v += part[i];
    #pragma unroll
    for (int off = 32; off > 0; off >>= 1) v += __shfl_down(v, off, 64);
    __shared__ double sh[NTHR / 64];
    int lane = threadIdx.x & 63, wid = threadIdx.x >> 6;
    if (lane == 0) sh[wid] = v;
    __syncthreads();
    if (threadIdx.x == 0) {
        double tot = 0.0;
        #pragma unroll
        for (int w = 0; w < NTHR / 64; ++w) tot += sh[w];
        out[0] = (float)(tot * inv_n);
    }
}

extern "C" void kernel_launch(void* const* d_in, const int* in_sizes, int n_in,
                              void* d_out, int out_size, void* d_ws, size_t ws_size,
                              hipStream_t stream) {
    const float* preds = (const float*)d_in[0];
    const float* targets = (const float*)d_in[1];
    float* out = (float*)d_out;

    // ws: part | fT fP sT sP (u64) | prT prP rcT rcP parentT parentP (int)
    //    | runsumT runsumP (f32)           (chunked by image)
    double* part = (double*)d_ws;
    char* base = (char*)d_ws + NPART * sizeof(double);
    size_t avail = (ws_size > NPART * sizeof(double)) ? ws_size - NPART * sizeof(double) : 0;
    const size_t wpi = (size_t)HH * WPR;       // 16384 words per image
    const size_t runs_pi = (size_t)HH * RPR;   // 524288 run slots per image
    const size_t per_img = 4 * wpi * sizeof(u64) + 2 * wpi * sizeof(int)
                         + 2 * HH * sizeof(int) + 2 * runs_pi * sizeof(int)
                         + 2 * runs_pi * sizeof(float);  // ~9.1 MB
    int chunk = (int)(avail / per_img);
    if (chunk < 1) chunk = 1;
    if (chunk > NB_TOTAL) chunk = NB_TOTAL;

    u64* fT = (u64*)base;
    u64* fP = fT + (size_t)chunk * wpi;
    u64* sT = fP + (size_t)chunk * wpi;
    u64* sP = sT + (size_t)chunk * wpi;
    int* prT = (int*)(sP + (size_t)chunk * wpi);
    int* prP = prT + (size_t)chunk * wpi;
    int* rcT = prP + (size_t)chunk * wpi;
    int* rcP = rcT + (size_t)chunk * HH;
    int* parentT = rcP + (size_t)chunk * HH;
    int* parentP = parentT + (size_t)chunk * runs_pi;
    float* runsumT = (float*)(parentP + (size_t)chunk * runs_pi);
    float* runsumP = runsumT + (size_t)chunk * runs_pi;

    k_zero<<<NPART / NTHR, NTHR, 0, stream>>>(part);

    for (int b0 = 0; b0 < NB_TOTAL; b0 += chunk) {
        int nb = (b0 + chunk <= NB_TOTAL) ? chunk : (NB_TOTAL - b0);
        long gbase = (long)b0 * IMGPIX;
        int nrows = nb * HH;
        int nslots = (int)(nb * runs_pi);

        k_maskloss<<<NBLK, NTHR, 0, stream>>>(preds, targets, gbase, nrows,
                                              fT, fP, sT, sP, prT, prP, rcT, rcP,
                                              runsumT, runsumP, part);
        k_strip<<<nb * STRIPS * 2, NTHR_S, 0, stream>>>(fT, fP, sT, sP, prT, prP,
                                                        rcT, rcP, parentT, parentP);
        k_bound<<<128, NTHR, 0, stream>>>(fT, fP, sT, sP, prT, prP, parentT, parentP, nb);
        k_accumrun<<<NBLK, NTHR, 0, stream>>>(rcT, rcP, parentT, parentP,
                                              runsumT, runsumP, part, nslots);
    }

    double inv_n = 1.0 / ((double)NB_TOTAL * (double)IMGPIX);
    k_final<<<1, NTHR, 0, stream>>>(part, out, inv_n);
}

// Round 11
// 289.177 us; speedup vs baseline: 1.0607x; 1.0607x over previous
//
#include <hip/hip_runtime.h>
#include <math.h>

// SuperVoxel critical-component loss on MI355X.
// mean( (0.5 + 0.25*neg + 0.25*pos) * bce_loss )
// Run-based two-level CCL with path-halving union-find and PER-RUN loss sums
// computed via register-only segmented wave scans (no LDS atomics).
//  k_maskloss: read floats ONCE -> fg masks, run starts/prefixes/counts,
//              per-run loss sums (segmented shfl scan + carry register),
//              0.5*sum(loss) base term.
//  k_strip:    32-row strips, intra-strip unions+flags in 64KB LDS,
//              used-slots-only, path-halving finds.
//  k_bound:    global flag-carrying unions on 31 strip seams per image.
//  k_accumrun: per used run slot: root flag ? 0.25*runsum : 0 -> partials.

#define HH 1024
#define WW 1024
#define IMGPIX (HH * WW)
#define NB_TOTAL 16
#define FLAGBIT 0x40000000
#define IDXMASK 0x3FFFFFFF
#define NBLK 2048
#define NPART 2048
#define NTHR 256
#define WPR 16               // u64 mask words per row
#define RPR 512              // run slots per row (hard worst case)
#define SROWS 32             // rows per strip
#define STRIPS (HH / SROWS)  // 32 strips per image
#define SLOTS (SROWS * RPR)  // 16384 slots per strip (64KB LDS)
#define NTHR_S 1024

typedef unsigned long long u64;

// ---------- global union-find, path-halving, flag-aware ----------
__device__ __forceinline__ int findRootH(int* p, int i) {
    volatile int* vp = p;
    int r = i;
    int e = vp[r] & IDXMASK;
    while (e != r) {
        int e2 = vp[e] & IDXMASK;
        if (e2 != e) p[r] = e2;  // shortcut: only non-roots written (no flags there)
        r = e; e = e2;
    }
    return r;
}

__device__ __forceinline__ void flagProp(int* p, int x) {
    while (true) {
        int r = findRootH(p, x);
        int old = atomicOr(&p[r], FLAGBIT);
        if ((old & IDXMASK) == r) return;  // was still a root
        x = old & IDXMASK;
    }
}

__device__ __forceinline__ void uniteGF(int* p, int a, int b) {
    int ra = findRootH(p, a), rb = findRootH(p, b);
    while (ra != rb) {
        if (ra < rb) { int t = ra; ra = rb; rb = t; }  // hook larger under smaller
        int e = p[ra];
        if ((e & IDXMASK) != ra) { ra = findRootH(p, e & IDXMASK); continue; }
        int prev = atomicCAS(&p[ra], e, rb);
        if (prev == e) {
            if (e & FLAGBIT) flagProp(p, rb);
            return;
        }
        ra = findRootH(p, prev & IDXMASK);
        rb = findRootH(p, rb);
    }
}

// ---------- LDS union-find, path-halving ----------
__device__ __forceinline__ int findRootL(int* lab, int i) {
    volatile int* vl = lab;
    int r = i;
    int e = vl[r] & IDXMASK;
    while (e != r) {
        int e2 = vl[e] & IDXMASK;
        if (e2 != e) lab[r] = e2;
        r = e; e = e2;
    }
    return r;
}

__device__ __forceinline__ void uniteL(int* lab, int a, int b) {
    int ra = findRootL(lab, a), rb = findRootL(lab, b);
    while (ra != rb) {
        if (ra < rb) { int t = ra; ra = rb; rb = t; }
        int prev = atomicCAS(&lab[ra], ra, rb);
        if (prev == ra) return;
        ra = findRootL(lab, prev & IDXMASK);
        rb = findRootL(lab, rb);
    }
}

// index (within row) of the run containing bit b of this word; requires fg@b.
__device__ __forceinline__ int runIndexW(u64 starts, int b) {
    u64 below = (2ULL << b) - 1ULL;  // b=63 wraps to ~0ULL
    return (int)__popcll(starts & below) - 1;
}

__global__ void k_zero(double* __restrict__ part) {
    part[blockIdx.x * blockDim.x + threadIdx.x] = 0.0;
}

// Wave-per-row: read floats once; run sums via segmented shfl scan; masks via
// lane-parallel shfl scan. No LDS beyond the final block reduce.
__global__ void k_maskloss(const float* __restrict__ preds, const float* __restrict__ targets,
                           long gbase, int nrows,
                           u64* __restrict__ fT, u64* __restrict__ fP,
                           u64* __restrict__ sT, u64* __restrict__ sP,
                           int* __restrict__ prT, int* __restrict__ prP,
                           int* __restrict__ rcT, int* __restrict__ rcP,
                           float* __restrict__ runsumT, float* __restrict__ runsumP,
                           double* __restrict__ part) {
    __shared__ double sh[4];
    int wid = threadIdx.x >> 6, lane = threadIdx.x & 63;
    const u64 beloweq = (2ULL << lane) - 1ULL;  // lane 63 -> ~0ULL
    double lsum = 0.0;
    for (int R = blockIdx.x * 4 + wid; R < nrows; R += gridDim.x * 4) {
        long pixbase = (long)R * WW;
        long rbase = (long)R * RPR;
        u64 myW = 0;  // lanes 0..15: T word[lane]; lanes 16..31: P word[lane-16]
        int cumT = 0, cumP = 0;
        u64 carryT = 0, carryP = 0;      // fg bit63 of previous word
        float csumT = 0.0f, csumP = 0.0f;  // pending (unterminated) run sums
        for (int w = 0; w < WPR; ++w) {
            long g = gbase + pixbase + w * 64 + lane;
            float p = preds[g], t = targets[g];
            float loss = fmaxf(p, 0.0f) - p * t + __logf(1.0f + __expf(-fabsf(p)));
            lsum += (double)loss;
            bool tf = t > 0.0f, pf = p > 0.5f;
            u64 bt = __ballot(tf);
            u64 bp = __ballot(pf);
            // ---- phase T: segmented run-sum scan ----
            {
                u64 st = bt & ~((bt << 1) | carryT);
                if (lane == 0 && carryT && !(bt & 1ULL))
                    runsumT[rbase + cumT - 1] = csumT;  // carry run terminated
                u64 mybelow = st & beloweq;
                bool hasst = mybelow != 0;
                int hpos = hasst ? (63 - __clzll(mybelow)) : 0;
                float v = tf ? loss : 0.0f;
                #pragma unroll
                for (int d = 1; d < 64; d <<= 1) {
                    float u = __shfl_up(v, d, 64);
                    if (lane >= d && (lane - d) >= hpos) v += u;
                }
                bool endhere = tf && lane < 63 && !((bt >> (lane + 1)) & 1ULL);
                if (endhere) {
                    float total = v + ((!hasst && carryT) ? csumT : 0.0f);
                    int idx = cumT + (int)__popcll(mybelow) - 1;  // !hasst -> cumT-1
                    runsumT[rbase + idx] = total;
                }
                float v63 = __shfl(v, 63, 64);
                float newcs = v63 + ((st == 0 && carryT) ? csumT : 0.0f);
                csumT = ((bt >> 63) & 1ULL) ? newcs : 0.0f;
                cumT += (int)__popcll(st);
                carryT = bt >> 63;
            }
            // ---- phase P: segmented run-sum scan ----
            {
                u64 st = bp & ~((bp << 1) | carryP);
                if (lane == 0 && carryP && !(bp & 1ULL))
                    runsumP[rbase + cumP - 1] = csumP;
                u64 mybelow = st & beloweq;
                bool hasst = mybelow != 0;
                int hpos = hasst ? (63 - __clzll(mybelow)) : 0;
                float v = pf ? loss : 0.0f;
                #pragma unroll
                for (int d = 1; d < 64; d <<= 1) {
                    float u = __shfl_up(v, d, 64);
                    if (lane >= d && (lane - d) >= hpos) v += u;
                }
                bool endhere = pf && lane < 63 && !((bp >> (lane + 1)) & 1ULL);
                if (endhere) {
                    float total = v + ((!hasst && carryP) ? csumP : 0.0f);
                    int idx = cumP + (int)__popcll(mybelow) - 1;
                    runsumP[rbase + idx] = total;
                }
                float v63 = __shfl(v, 63, 64);
                float newcs = v63 + ((st == 0 && carryP) ? csumP : 0.0f);
                csumP = ((bp >> 63) & 1ULL) ? newcs : 0.0f;
                cumP += (int)__popcll(st);
                carryP = bp >> 63;
            }
            if (lane == w) myW = bt;
            if (lane == w + 16) myW = bp;
        }
        // end-of-row pending runs
        if (lane == 0) {
            if (carryT) runsumT[rbase + cumT - 1] = csumT;
            if (carryP) runsumP[rbase + cumP - 1] = csumP;
        }
        // masks / starts / prefixes via lane-parallel shfl scan (lanes < 32)
        if (lane < 32) {
            int subid = lane & 15;
            u64 prevW = __shfl_up(myW, 1, 16);
            u64 carry = (subid > 0) ? (prevW >> 63) : 0ULL;
            u64 st = myW & ~((myW << 1) | carry);
            int cnt = (int)__popcll(st);
            int incl = cnt;
            #pragma unroll
            for (int d = 1; d < 16; d <<= 1) {
                int v = __shfl_up(incl, d, 16);
                if (subid >= d) incl += v;
            }
            int excl = incl - cnt;
            int wi = R * WPR + subid;
            if (lane < 16) {
                fT[wi] = myW; sT[wi] = st; prT[wi] = excl;
                if (subid == 15) rcT[R] = incl;
            } else {
                fP[wi] = myW; sP[wi] = st; prP[wi] = excl;
                if (subid == 15) rcP[R] = incl;
            }
        }
    }
    lsum *= 0.5;
    #pragma unroll
    for (int off = 32; off > 0; off >>= 1) lsum += __shfl_down(lsum, off, 64);
    if (lane == 0) sh[wid] = lsum;
    __syncthreads();
    if (threadIdx.x == 0) part[blockIdx.x] += sh[0] + sh[1] + sh[2] + sh[3];
}

// One block per (image, strip, phase): intra-strip CCL + flags in 64KB LDS.
__global__ __launch_bounds__(NTHR_S) void
k_strip(const u64* __restrict__ fT, const u64* __restrict__ fP,
        const u64* __restrict__ sT, const u64* __restrict__ sP,
        const int* __restrict__ prT, const int* __restrict__ prP,
        const int* __restrict__ rcT, const int* __restrict__ rcP,
        int* __restrict__ parentT, int* __restrict__ parentP) {
    __shared__ int lab[SLOTS];
    __shared__ int rcL[SROWS];
    int bid = blockIdx.x;
    int ph = bid & 1; bid >>= 1;
    int strip = bid & (STRIPS - 1);
    int img = bid >> 5;  // STRIPS = 32
    const u64* f = ph ? fP : fT;
    const u64* fB = ph ? fT : fP;
    const u64* s = ph ? sP : sT;
    const int* pr = ph ? prP : prT;
    const int* rc = ph ? rcP : rcT;
    int* parent = ph ? parentP : parentT;
    const int row0 = img * HH + strip * SROWS;

    if (threadIdx.x < SROWS) rcL[threadIdx.x] = rc[row0 + threadIdx.x];
    __syncthreads();

    // init used slots only
    for (int i = threadIdx.x; i < SLOTS; i += NTHR_S)
        if ((i & (RPR - 1)) < rcL[i >> 9]) lab[i] = i;
    __syncthreads();

    // intra-strip vertical unites, 2-way sub-word split
    for (int task = threadIdx.x; task < (SROWS - 1) * WPR * 2; task += NTHR_S) {
        int j = task & 1, w = (task >> 1) & 15, r = task >> 5;
        int w0 = (row0 + r) * WPR + w, w1 = w0 + WPR;
        u64 o = f[w0] & f[w1];
        if (!o) continue;
        u64 s0 = s[w0], s1 = s[w1];
        int b0 = r * RPR + pr[w0], b1 = (r + 1) * RPR + pr[w1];
        u64 os = o & ~(o << 1);
        int k = 0;
        while (os) {
            int b = __builtin_ctzll(os);
            os &= os - 1;
            if ((k++ & 1) == j)
                uniteL(lab, b0 + runIndexW(s0, b), b1 + runIndexW(s1, b));
        }
    }
    __syncthreads();

    // mistake flags onto local roots, 2-way sub-word split
    for (int task = threadIdx.x; task < SROWS * WPR * 2; task += NTHR_S) {
        int j = task & 1, w = (task >> 1) & 15, r = task >> 5;
        int wi = (row0 + r) * WPR + w;
        u64 m = f[wi] & ~fB[wi];
        if (!m) continue;
        u64 sw = s[wi];
        int base = r * RPR + pr[wi];
        u64 ms = m & ~(m << 1);
        int k = 0, last = -1;
        while (ms) {
            int b = __builtin_ctzll(ms);
            ms &= ms - 1;
            if ((k++ & 1) != j) continue;
            int rid = base + runIndexW(sw, b);
            if (rid == last) continue;
            last = rid;
            int rt = findRootL(lab, rid);
            if (!(((volatile int*)lab)[rt] & FLAGBIT)) atomicOr(&lab[rt], FLAGBIT);
        }
    }
    __syncthreads();

    // compress + write used slots (root entries carry flag)
    const int gb = row0 * RPR;
    for (int i = threadIdx.x; i < SLOTS; i += NTHR_S) {
        if ((i & (RPR - 1)) >= rcL[i >> 9]) continue;
        int e = lab[i];
        int rt = e & IDXMASK;
        if (rt != i) rt = findRootL(lab, rt);
        parent[gb + i] = (rt == i) ? ((gb + i) | (e & FLAGBIT)) : (gb + rt);
    }
}

// Global flag-carrying unions across the 31 strip seams per image.
__global__ void k_bound(const u64* __restrict__ fT, const u64* __restrict__ fP,
                        const u64* __restrict__ sT, const u64* __restrict__ sP,
                        const int* __restrict__ prT, const int* __restrict__ prP,
                        int* __restrict__ parentT, int* __restrict__ parentP, int nb) {
    int tasks = nb * (STRIPS - 1) * WPR * 2;
    int stride = gridDim.x * blockDim.x;
    for (int id = blockIdx.x * blockDim.x + threadIdx.x; id < tasks; id += stride) {
        int ph = id & 1;
        int t = id >> 1;
        int w = t & 15; t >>= 4;
        int bnd = t % (STRIPS - 1);
        int img = t / (STRIPS - 1);
        int R = img * HH + bnd * SROWS + (SROWS - 1);  // last row of strip bnd
        const u64* f = ph ? fP : fT;
        const u64* s = ph ? sP : sT;
        const int* pr = ph ? prP : prT;
        int* parent = ph ? parentP : parentT;
        int w0 = R * WPR + w, w1 = w0 + WPR;
        u64 o = f[w0] & f[w1];
        if (!o) continue;
        u64 s0 = s[w0], s1 = s[w1];
        int b0 = R * RPR + pr[w0], b1 = (R + 1) * RPR + pr[w1];
        u64 os = o & ~(o << 1);
        while (os) {
            int b = __builtin_ctzll(os);
            os &= os - 1;
            uniteGF(parent, b0 + runIndexW(s0, b), b1 + runIndexW(s1, b));
        }
    }
}

// Per used run slot: if final root flagged, add 0.25*runsum. -> partials.
__global__ void k_accumrun(const int* __restrict__ rcT, const int* __restrict__ rcP,
                           int* __restrict__ parentT, int* __restrict__ parentP,
                           const float* __restrict__ runsumT, const float* __restrict__ runsumP,
                           double* __restrict__ part, int nslots) {
    int stride = gridDim.x * blockDim.x;
    double local = 0.0;
    for (int i = blockIdx.x * blockDim.x + threadIdx.x; i < nslots; i += stride) {
        int row = i >> 9, k = i & (RPR - 1);
        if (k < rcT[row]) {
            int e = parentT[i];
            int r = e & IDXMASK;
            int fl;
            if (r == i) fl = e & FLAGBIT;
            else { r = findRootH(parentT, r); fl = parentT[r] & FLAGBIT; }
            if (fl) local += 0.25 * (double)runsumT[i];
        }
        if (k < rcP[row]) {
            int e = parentP[i];
            int r = e & IDXMASK;
            int fl;
            if (r == i) fl = e & FLAGBIT;
            else { r = findRootH(parentP, r); fl = parentP[r] & FLAGBIT; }
            if (fl) local += 0.25 * (double)runsumP[i];
        }
    }
    #pragma unroll
    for (int off = 32; off > 0; off >>= 1) local += __shfl_down(local, off, 64);
    __shared__ double sh[NTHR / 64];
    int lane = threadIdx.x & 63, wid = threadIdx.x >> 6;
    if (lane == 0) sh[wid] = local;
    __syncthreads();
    if (threadIdx.x == 0) {
        double tot = 0.0;
        #pragma unroll
        for (int w = 0; w < NTHR / 64; ++w) tot += sh[w];
        part[blockIdx.x] += tot;
    }
}

__global__ void k_final(const double* __restrict__ part, float* __restrict__ out, double inv_n) {
    double v = 0.0;
    for (int i = threadIdx.x; i < NPART; i += blockDim.x) v += part[i];
    #pragma unroll
    for (int off = 32; off > 0; off >>= 1) v += __shfl_down(v, off, 64);
    __shared__ double sh[NTHR / 64];
    int lane = threadIdx.x & 63, wid = threadIdx.x >> 6;
    if (lane == 0) sh[wid] = v;
    __syncthreads();
    if (threadIdx.x == 0) {
        double tot = 0.0;
        #pragma unroll
        for (int w = 0; w < NTHR / 64; ++w) tot += sh[w];
        out[0] = (float)(tot * inv_n);
    }
}

extern "C" void kernel_launch(void* const* d_in, const int* in_sizes, int n_in,
                              void* d_out, int out_size, void* d_ws, size_t ws_size,
                              hipStream_t stream) {
    const float* preds = (const float*)d_in[0];
    const float* targets = (const float*)d_in[1];
    float* out = (float*)d_out;

    // ws: part | fT fP sT sP (u64) | prT prP rcT rcP parentT parentP (int)
    //    | runsumT runsumP (f32)           (chunked by image)
    double* part = (double*)d_ws;
    char* base = (char*)d_ws + NPART * sizeof(double);
    size_t avail = (ws_size > NPART * sizeof(double)) ? ws_size - NPART * sizeof(double) : 0;
    const size_t wpi = (size_t)HH * WPR;       // 16384 words per image
    const size_t runs_pi = (size_t)HH * RPR;   // 524288 run slots per image
    const size_t per_img = 4 * wpi * sizeof(u64) + 2 * wpi * sizeof(int)
                         + 2 * HH * sizeof(int) + 2 * runs_pi * sizeof(int)
                         + 2 * runs_pi * sizeof(float);  // ~9.1 MB
    int chunk = (int)(avail / per_img);
    if (chunk < 1) chunk = 1;
    if (chunk > NB_TOTAL) chunk = NB_TOTAL;

    u64* fT = (u64*)base;
    u64* fP = fT + (size_t)chunk * wpi;
    u64* sT = fP + (size_t)chunk * wpi;
    u64* sP = sT + (size_t)chunk * wpi;
    int* prT = (int*)(sP + (size_t)chunk * wpi);
    int* prP = prT + (size_t)chunk * wpi;
    int* rcT = prP + (size_t)chunk * wpi;
    int* rcP = rcT + (size_t)chunk * HH;
    int* parentT = rcP + (size_t)chunk * HH;
    int* parentP = parentT + (size_t)chunk * runs_pi;
    float* runsumT = (float*)(parentP + (size_t)chunk * runs_pi);
    float* runsumP = runsumT + (size_t)chunk * runs_pi;

    k_zero<<<NPART / NTHR, NTHR, 0, stream>>>(part);

    for (int b0 = 0; b0 < NB_TOTAL; b0 += chunk) {
        int nb = (b0 + chunk <= NB_TOTAL) ? chunk : (NB_TOTAL - b0);
        long gbase = (long)b0 * IMGPIX;
        int nrows = nb * HH;
        int nslots = (int)(nb * runs_pi);

        k_maskloss<<<NBLK, NTHR, 0, stream>>>(preds, targets, gbase, nrows,
                                              fT, fP, sT, sP, prT, prP, rcT, rcP,
                                              runsumT, runsumP, part);
        k_strip<<<nb * STRIPS * 2, NTHR_S, 0, stream>>>(fT, fP, sT, sP, prT, prP,
                                                        rcT, rcP, parentT, parentP);
        k_bound<<<128, NTHR, 0, stream>>>(fT, fP, sT, sP, prT, prP, parentT, parentP, nb);
        k_accumrun<<<NBLK, NTHR, 0, stream>>>(rcT, rcP, parentT, parentP,
                                              runsumT, runsumP, part, nslots);
    }

    double inv_n = 1.0 / ((double)NB_TOTAL * (double)IMGPIX);
    k_final<<<1, NTHR, 0, stream>>>(part, out, inv_n);
}

// Round 12
// 256.773 us; speedup vs baseline: 1.1945x; 1.1262x over previous
//
#include <hip/hip_runtime.h>
#include <math.h>

// SuperVoxel critical-component loss on MI355X.
// mean( (0.5 + 0.25*neg + 0.25*pos) * bce_loss )
// Run-based two-level CCL with path-halving union-find and PER-RUN loss sums.
//  k_maskloss: lane-chunk layout (16 px/lane). Masks/starts = register bit
//              math; in-lane runs = serial register loop; cross-lane runs via
//              ONE count scan + ONE segmented sum scan per row per phase.
//              Continuing-run id = base_l - 1 (exclusive-scan property).
//  k_strip:    32-row strips, intra-strip unions+flags in 64KB LDS,
//              used-slots-only, path-halving finds.  (unchanged, verified)
//  k_bound:    global flag-carrying unions on 31 strip seams per image.
//  k_accumrun: per used run slot: root flag ? 0.25*runsum : 0 -> partials.

#define HH 1024
#define WW 1024
#define IMGPIX (HH * WW)
#define NB_TOTAL 16
#define FLAGBIT 0x40000000
#define IDXMASK 0x3FFFFFFF
#define NBLK 2048
#define NPART 2048
#define NTHR 256
#define WPR 16               // u64 mask words per row
#define RPR 512              // run slots per row (hard worst case)
#define SROWS 32             // rows per strip
#define STRIPS (HH / SROWS)  // 32 strips per image
#define SLOTS (SROWS * RPR)  // 16384 slots per strip (64KB LDS)
#define NTHR_S 1024

typedef unsigned long long u64;

// ---------- global union-find, path-halving, flag-aware ----------
__device__ __forceinline__ int findRootH(int* p, int i) {
    volatile int* vp = p;
    int r = i;
    int e = vp[r] & IDXMASK;
    while (e != r) {
        int e2 = vp[e] & IDXMASK;
        if (e2 != e) p[r] = e2;  // shortcut: only non-roots written (no flags there)
        r = e; e = e2;
    }
    return r;
}

__device__ __forceinline__ void flagProp(int* p, int x) {
    while (true) {
        int r = findRootH(p, x);
        int old = atomicOr(&p[r], FLAGBIT);
        if ((old & IDXMASK) == r) return;  // was still a root
        x = old & IDXMASK;
    }
}

__device__ __forceinline__ void uniteGF(int* p, int a, int b) {
    int ra = findRootH(p, a), rb = findRootH(p, b);
    while (ra != rb) {
        if (ra < rb) { int t = ra; ra = rb; rb = t; }  // hook larger under smaller
        int e = p[ra];
        if ((e & IDXMASK) != ra) { ra = findRootH(p, e & IDXMASK); continue; }
        int prev = atomicCAS(&p[ra], e, rb);
        if (prev == e) {
            if (e & FLAGBIT) flagProp(p, rb);
            return;
        }
        ra = findRootH(p, prev & IDXMASK);
        rb = findRootH(p, rb);
    }
}

// ---------- LDS union-find, path-halving ----------
__device__ __forceinline__ int findRootL(int* lab, int i) {
    volatile int* vl = lab;
    int r = i;
    int e = vl[r] & IDXMASK;
    while (e != r) {
        int e2 = vl[e] & IDXMASK;
        if (e2 != e) lab[r] = e2;
        r = e; e = e2;
    }
    return r;
}

__device__ __forceinline__ void uniteL(int* lab, int a, int b) {
    int ra = findRootL(lab, a), rb = findRootL(lab, b);
    while (ra != rb) {
        if (ra < rb) { int t = ra; ra = rb; rb = t; }
        int prev = atomicCAS(&lab[ra], ra, rb);
        if (prev == ra) return;
        ra = findRootL(lab, prev & IDXMASK);
        rb = findRootL(lab, rb);
    }
}

// index (within row) of the run containing bit b of this word; requires fg@b.
__device__ __forceinline__ int runIndexW(u64 starts, int b) {
    u64 below = (2ULL << b) - 1ULL;  // b=63 wraps to ~0ULL
    return (int)__popcll(starts & below) - 1;
}

__global__ void k_zero(double* __restrict__ part) {
    part[blockIdx.x * blockDim.x + threadIdx.x] = 0.0;
}

// Per-phase processing for one lane's 16-pixel chunk. Returns starts/excl.
__device__ __forceinline__ void phaseRuns(int lane, int mask, const float* lossv,
                                          long rbase, float* __restrict__ runsum,
                                          int* __restrict__ rcOut, int R,
                                          int& startsOut, int& exclOut) {
    int prevm = __shfl_up(mask, 1, 64);
    int carry = (lane == 0) ? 0 : ((prevm >> 15) & 1);
    int starts = mask & ~((mask << 1) | carry) & 0xFFFF;
    int cnt = __popc(starts);
    // count scan (once per row per phase)
    int incl = cnt;
    #pragma unroll
    for (int d = 1; d < 64; d <<= 1) {
        int u = __shfl_up(incl, d, 64);
        if (lane >= d) incl += u;
    }
    int excl = incl - cnt;
    // serial in-lane pass: complete runs write directly
    float cur = 0.0f, headsum = 0.0f;
    bool begun = false, prevfg = (carry != 0), hasHead = false;
    int scount = 0;
    #pragma unroll
    for (int k = 0; k < 16; ++k) {
        bool fg = (mask >> k) & 1;
        if (fg) {
            if ((starts >> k) & 1) { cur = lossv[k]; begun = true; ++scount; }
            else cur += lossv[k];
        } else {
            if (prevfg) {
                if (begun) runsum[rbase + excl + scount - 1] = cur;
                else { hasHead = true; headsum = cur; }
            }
        }
        prevfg = fg;
    }
    // segmented sum scan for cross-lane runs
    float sv = prevfg ? cur : 0.0f;
    int fl = (starts != 0);
    #pragma unroll
    for (int d = 1; d < 64; d <<= 1) {
        float u = __shfl_up(sv, d, 64);
        int uf = __shfl_up(fl, d, 64);
        if (lane >= d) {
            if (!fl) sv += u;
            fl |= uf;
        }
    }
    float svprev = __shfl_up(sv, 1, 64);
    if (hasHead) runsum[rbase + excl - 1] = svprev + headsum;  // run continuing into this lane ends here
    if (lane == 63) {
        if (prevfg) runsum[rbase + incl - 1] = sv;  // run ends at row end
        rcOut[R] = incl;
    }
    startsOut = starts;
    exclOut = excl;
}

// Wave-per-row, lane-chunk layout: lane l owns pixels [16l, 16l+16).
__global__ void k_maskloss(const float* __restrict__ preds, const float* __restrict__ targets,
                           long gbase, int nrows,
                           u64* __restrict__ fT, u64* __restrict__ fP,
                           u64* __restrict__ sT, u64* __restrict__ sP,
                           int* __restrict__ prT, int* __restrict__ prP,
                           int* __restrict__ rcT, int* __restrict__ rcP,
                           float* __restrict__ runsumT, float* __restrict__ runsumP,
                           double* __restrict__ part) {
    __shared__ double sh[4];
    int wid = threadIdx.x >> 6, lane = threadIdx.x & 63;
    double lsum = 0.0;
    for (int R = blockIdx.x * 4 + wid; R < nrows; R += gridDim.x * 4) {
        long pixbase = (long)R * WW;
        long rbase = (long)R * RPR;
        const float4* p4 = (const float4*)(preds + gbase + pixbase);
        const float4* t4 = (const float4*)(targets + gbase + pixbase);
        float lossv[16];
        int maskT = 0, maskP = 0;
        float rowsum = 0.0f;
        #pragma unroll
        for (int j = 0; j < 4; ++j) {
            float4 pv = p4[lane * 4 + j];
            float4 tv = t4[lane * 4 + j];
            float pp[4] = {pv.x, pv.y, pv.z, pv.w};
            float tt[4] = {tv.x, tv.y, tv.z, tv.w};
            #pragma unroll
            for (int q = 0; q < 4; ++q) {
                int k = j * 4 + q;
                float p = pp[q], t = tt[q];
                float loss = fmaxf(p, 0.0f) - p * t + __logf(1.0f + __expf(-fabsf(p)));
                lossv[k] = loss;
                rowsum += loss;
                maskT |= ((int)(t > 0.0f)) << k;
                maskP |= ((int)(p > 0.5f)) << k;
            }
        }
        lsum += (double)rowsum;

        int stT_, exT, stP_, exP;
        phaseRuns(lane, maskT, lossv, rbase, runsumT, rcT, R, stT_, exT);
        phaseRuns(lane, maskP, lossv, rbase, runsumP, rcP, R, stP_, exP);

        // pack word-format outputs: lanes 0..15 -> T words, 16..31 -> P words
        int subid = lane & 15;
        int srcl = subid * 4;
        u64 fw = 0, sw = 0;
        #pragma unroll
        for (int j = 0; j < 4; ++j) {
            int mT = __shfl(maskT, srcl + j, 64);
            int mP = __shfl(maskP, srcl + j, 64);
            int aT = __shfl(stT_, srcl + j, 64);
            int aP = __shfl(stP_, srcl + j, 64);
            u64 m = (u64)(unsigned)((lane < 16) ? mT : mP);
            u64 a = (u64)(unsigned)((lane < 16) ? aT : aP);
            fw |= m << (16 * j);
            sw |= a << (16 * j);
        }
        int eT = __shfl(exT, srcl, 64);
        int eP = __shfl(exP, srcl, 64);
        int wi = R * WPR + subid;
        if (lane < 16) { fT[wi] = fw; sT[wi] = sw; prT[wi] = eT; }
        else if (lane < 32) { fP[wi] = fw; sP[wi] = sw; prP[wi] = eP; }
    }
    lsum *= 0.5;
    #pragma unroll
    for (int off = 32; off > 0; off >>= 1) lsum += __shfl_down(lsum, off, 64);
    if (lane == 0) sh[wid] = lsum;
    __syncthreads();
    if (threadIdx.x == 0) part[blockIdx.x] += sh[0] + sh[1] + sh[2] + sh[3];
}

// One block per (image, strip, phase): intra-strip CCL + flags in 64KB LDS.
__global__ __launch_bounds__(NTHR_S) void
k_strip(const u64* __restrict__ fT, const u64* __restrict__ fP,
        const u64* __restrict__ sT, const u64* __restrict__ sP,
        const int* __restrict__ prT, const int* __restrict__ prP,
        const int* __restrict__ rcT, const int* __restrict__ rcP,
        int* __restrict__ parentT, int* __restrict__ parentP) {
    __shared__ int lab[SLOTS];
    __shared__ int rcL[SROWS];
    int bid = blockIdx.x;
    int ph = bid & 1; bid >>= 1;
    int strip = bid & (STRIPS - 1);
    int img = bid >> 5;  // STRIPS = 32
    const u64* f = ph ? fP : fT;
    const u64* fB = ph ? fT : fP;
    const u64* s = ph ? sP : sT;
    const int* pr = ph ? prP : prT;
    const int* rc = ph ? rcP : rcT;
    int* parent = ph ? parentP : parentT;
    const int row0 = img * HH + strip * SROWS;

    if (threadIdx.x < SROWS) rcL[threadIdx.x] = rc[row0 + threadIdx.x];
    __syncthreads();

    // init used slots only
    for (int i = threadIdx.x; i < SLOTS; i += NTHR_S)
        if ((i & (RPR - 1)) < rcL[i >> 9]) lab[i] = i;
    __syncthreads();

    // intra-strip vertical unites, 2-way sub-word split
    for (int task = threadIdx.x; task < (SROWS - 1) * WPR * 2; task += NTHR_S) {
        int j = task & 1, w = (task >> 1) & 15, r = task >> 5;
        int w0 = (row0 + r) * WPR + w, w1 = w0 + WPR;
        u64 o = f[w0] & f[w1];
        if (!o) continue;
        u64 s0 = s[w0], s1 = s[w1];
        int b0 = r * RPR + pr[w0], b1 = (r + 1) * RPR + pr[w1];
        u64 os = o & ~(o << 1);
        int k = 0;
        while (os) {
            int b = __builtin_ctzll(os);
            os &= os - 1;
            if ((k++ & 1) == j)
                uniteL(lab, b0 + runIndexW(s0, b), b1 + runIndexW(s1, b));
        }
    }
    __syncthreads();

    // mistake flags onto local roots, 2-way sub-word split
    for (int task = threadIdx.x; task < SROWS * WPR * 2; task += NTHR_S) {
        int j = task & 1, w = (task >> 1) & 15, r = task >> 5;
        int wi = (row0 + r) * WPR + w;
        u64 m = f[wi] & ~fB[wi];
        if (!m) continue;
        u64 sw = s[wi];
        int base = r * RPR + pr[wi];
        u64 ms = m & ~(m << 1);
        int k = 0, last = -1;
        while (ms) {
            int b = __builtin_ctzll(ms);
            ms &= ms - 1;
            if ((k++ & 1) != j) continue;
            int rid = base + runIndexW(sw, b);
            if (rid == last) continue;
            last = rid;
            int rt = findRootL(lab, rid);
            if (!(((volatile int*)lab)[rt] & FLAGBIT)) atomicOr(&lab[rt], FLAGBIT);
        }
    }
    __syncthreads();

    // compress + write used slots (root entries carry flag)
    const int gb = row0 * RPR;
    for (int i = threadIdx.x; i < SLOTS; i += NTHR_S) {
        if ((i & (RPR - 1)) >= rcL[i >> 9]) continue;
        int e = lab[i];
        int rt = e & IDXMASK;
        if (rt != i) rt = findRootL(lab, rt);
        parent[gb + i] = (rt == i) ? ((gb + i) | (e & FLAGBIT)) : (gb + rt);
    }
}

// Global flag-carrying unions across the 31 strip seams per image.
__global__ void k_bound(const u64* __restrict__ fT, const u64* __restrict__ fP,
                        const u64* __restrict__ sT, const u64* __restrict__ sP,
                        const int* __restrict__ prT, const int* __restrict__ prP,
                        int* __restrict__ parentT, int* __restrict__ parentP, int nb) {
    int tasks = nb * (STRIPS - 1) * WPR * 2;
    int stride = gridDim.x * blockDim.x;
    for (int id = blockIdx.x * blockDim.x + threadIdx.x; id < tasks; id += stride) {
        int ph = id & 1;
        int t = id >> 1;
        int w = t & 15; t >>= 4;
        int bnd = t % (STRIPS - 1);
        int img = t / (STRIPS - 1);
        int R = img * HH + bnd * SROWS + (SROWS - 1);  // last row of strip bnd
        const u64* f = ph ? fP : fT;
        const u64* s = ph ? sP : sT;
        const int* pr = ph ? prP : prT;
        int* parent = ph ? parentP : parentT;
        int w0 = R * WPR + w, w1 = w0 + WPR;
        u64 o = f[w0] & f[w1];
        if (!o) continue;
        u64 s0 = s[w0], s1 = s[w1];
        int b0 = R * RPR + pr[w0], b1 = (R + 1) * RPR + pr[w1];
        u64 os = o & ~(o << 1);
        while (os) {
            int b = __builtin_ctzll(os);
            os &= os - 1;
            uniteGF(parent, b0 + runIndexW(s0, b), b1 + runIndexW(s1, b));
        }
    }
}

// Per used run slot: if final root flagged, add 0.25*runsum. -> partials.
__global__ void k_accumrun(const int* __restrict__ rcT, const int* __restrict__ rcP,
                           int* __restrict__ parentT, int* __restrict__ parentP,
                           const float* __restrict__ runsumT, const float* __restrict__ runsumP,
                           double* __restrict__ part, int nslots) {
    int stride = gridDim.x * blockDim.x;
    double local = 0.0;
    for (int i = blockIdx.x * blockDim.x + threadIdx.x; i < nslots; i += stride) {
        int row = i >> 9, k = i & (RPR - 1);
        if (k < rcT[row]) {
            int e = parentT[i];
            int r = e & IDXMASK;
            int fl;
            if (r == i) fl = e & FLAGBIT;
            else { r = findRootH(parentT, r); fl = parentT[r] & FLAGBIT; }
            if (fl) local += 0.25 * (double)runsumT[i];
        }
        if (k < rcP[row]) {
            int e = parentP[i];
            int r = e & IDXMASK;
            int fl;
            if (r == i) fl = e & FLAGBIT;
            else { r = findRootH(parentP, r); fl = parentP[r] & FLAGBIT; }
            if (fl) local += 0.25 * (double)runsumP[i];
        }
    }
    #pragma unroll
    for (int off = 32; off > 0; off >>= 1) local += __shfl_down(local, off, 64);
    __shared__ double sh[NTHR / 64];
    int lane = threadIdx.x & 63, wid = threadIdx.x >> 6;
    if (lane == 0) sh[wid] = local;
    __syncthreads();
    if (threadIdx.x == 0) {
        double tot = 0.0;
        #pragma unroll
        for (int w = 0; w < NTHR / 64; ++w) tot += sh[w];
        part[blockIdx.x] += tot;
    }
}

__global__ void k_final(const double* __restrict__ part, float* __restrict__ out, double inv_n) {
    double v = 0.0;
    for (int i = threadIdx.x; i < NPART; i += blockDim.x) v += part[i];
    #pragma unroll
    for (int off = 32; off > 0; off >>= 1) v += __shfl_down(v, off, 64);
    __shared__ double sh[NTHR / 64];
    int lane = threadIdx.x & 63, wid = threadIdx.x >> 6;
    if (lane == 0) sh[wid] = v;
    __syncthreads();
    if (threadIdx.x == 0) {
        double tot = 0.0;
        #pragma unroll
        for (int w = 0; w < NTHR / 64; ++w) tot += sh[w];
        out[0] = (float)(tot * inv_n);
    }
}

extern "C" void kernel_launch(void* const* d_in, const int* in_sizes, int n_in,
                              void* d_out, int out_size, void* d_ws, size_t ws_size,
                              hipStream_t stream) {
    const float* preds = (const float*)d_in[0];
    const float* targets = (const float*)d_in[1];
    float* out = (float*)d_out;

    // ws: part | fT fP sT sP (u64) | prT prP rcT rcP parentT parentP (int)
    //    | runsumT runsumP (f32)           (chunked by image)
    double* part = (double*)d_ws;
    char* base = (char*)d_ws + NPART * sizeof(double);
    size_t avail = (ws_size > NPART * sizeof(double)) ? ws_size - NPART * sizeof(double) : 0;
    const size_t wpi = (size_t)HH * WPR;       // 16384 words per image
    const size_t runs_pi = (size_t)HH * RPR;   // 524288 run slots per image
    const size_t per_img = 4 * wpi * sizeof(u64) + 2 * wpi * sizeof(int)
                         + 2 * HH * sizeof(int) + 2 * runs_pi * sizeof(int)
                         + 2 * runs_pi * sizeof(float);  // ~9.1 MB
    int chunk = (int)(avail / per_img);
    if (chunk < 1) chunk = 1;
    if (chunk > NB_TOTAL) chunk = NB_TOTAL;

    u64* fT = (u64*)base;
    u64* fP = fT + (size_t)chunk * wpi;
    u64* sT = fP + (size_t)chunk * wpi;
    u64* sP = sT + (size_t)chunk * wpi;
    int* prT = (int*)(sP + (size_t)chunk * wpi);
    int* prP = prT + (size_t)chunk * wpi;
    int* rcT = prP + (size_t)chunk * wpi;
    int* rcP = rcT + (size_t)chunk * HH;
    int* parentT = rcP + (size_t)chunk * HH;
    int* parentP = parentT + (size_t)chunk * runs_pi;
    float* runsumT = (float*)(parentP + (size_t)chunk * runs_pi);
    float* runsumP = runsumT + (size_t)chunk * runs_pi;

    k_zero<<<NPART / NTHR, NTHR, 0, stream>>>(part);

    for (int b0 = 0; b0 < NB_TOTAL; b0 += chunk) {
        int nb = (b0 + chunk <= NB_TOTAL) ? chunk : (NB_TOTAL - b0);
        long gbase = (long)b0 * IMGPIX;
        int nrows = nb * HH;
        int nslots = (int)(nb * runs_pi);

        k_maskloss<<<NBLK, NTHR, 0, stream>>>(preds, targets, gbase, nrows,
                                              fT, fP, sT, sP, prT, prP, rcT, rcP,
                                              runsumT, runsumP, part);
        k_strip<<<nb * STRIPS * 2, NTHR_S, 0, stream>>>(fT, fP, sT, sP, prT, prP,
                                                        rcT, rcP, parentT, parentP);
        k_bound<<<128, NTHR, 0, stream>>>(fT, fP, sT, sP, prT, prP, parentT, parentP, nb);
        k_accumrun<<<NBLK, NTHR, 0, stream>>>(rcT, rcP, parentT, parentP,
                                              runsumT, runsumP, part, nslots);
    }

    double inv_n = 1.0 / ((double)NB_TOTAL * (double)IMGPIX);
    k_final<<<1, NTHR, 0, stream>>>(part, out, inv_n);
}

// Round 13
// 243.767 us; speedup vs baseline: 1.2583x; 1.0534x over previous
//
#include <hip/hip_runtime.h>
#include <math.h>

// SuperVoxel critical-component loss on MI355X.
// mean( (0.5 + 0.25*neg + 0.25*pos) * bce_loss )
// Run-based two-level CCL with path-halving union-find and PER-RUN loss sums.
//  k_maskloss: lane-chunk layout (16 px/lane). Masks/starts = register bit
//              math; run sums via serial in-lane loop + ONE segmented scan.
//              Run's "contains mistake" bit packed into runsum SIGN.
//  k_strip:    32-row strips, intra-strip unions in 64KB LDS. NO separate
//              flag pass: compress pass A uses its own find to OR the
//              sign-bit mistake flag onto the (static) root.
//  k_bound:    global flag-carrying unions on 31 strip seams per image.
//  k_accumrun: per used run slot (x4 vectorized): root flag ? 0.25*|runsum|.

#define HH 1024
#define WW 1024
#define IMGPIX (HH * WW)
#define NB_TOTAL 16
#define FLAGBIT 0x40000000
#define IDXMASK 0x3FFFFFFF
#define NBLK 2048
#define NPART 2048
#define NTHR 256
#define WPR 16               // u64 mask words per row
#define RPR 512              // run slots per row (hard worst case)
#define SROWS 32             // rows per strip
#define STRIPS (HH / SROWS)  // 32 strips per image
#define SLOTS (SROWS * RPR)  // 16384 slots per strip (64KB LDS)
#define NTHR_S 1024

typedef unsigned long long u64;

// ---------- global union-find, path-halving, flag-aware ----------
__device__ __forceinline__ int findRootH(int* p, int i) {
    volatile int* vp = p;
    int r = i;
    int e = vp[r] & IDXMASK;
    while (e != r) {
        int e2 = vp[e] & IDXMASK;
        if (e2 != e) p[r] = e2;  // shortcut: only non-roots written (no flags there)
        r = e; e = e2;
    }
    return r;
}

__device__ __forceinline__ void flagProp(int* p, int x) {
    while (true) {
        int r = findRootH(p, x);
        int old = atomicOr(&p[r], FLAGBIT);
        if ((old & IDXMASK) == r) return;  // was still a root
        x = old & IDXMASK;
    }
}

__device__ __forceinline__ void uniteGF(int* p, int a, int b) {
    int ra = findRootH(p, a), rb = findRootH(p, b);
    while (ra != rb) {
        if (ra < rb) { int t = ra; ra = rb; rb = t; }  // hook larger under smaller
        int e = p[ra];
        if ((e & IDXMASK) != ra) { ra = findRootH(p, e & IDXMASK); continue; }
        int prev = atomicCAS(&p[ra], e, rb);
        if (prev == e) {
            if (e & FLAGBIT) flagProp(p, rb);
            return;
        }
        ra = findRootH(p, prev & IDXMASK);
        rb = findRootH(p, rb);
    }
}

// ---------- LDS union-find, path-halving ----------
__device__ __forceinline__ int findRootL(int* lab, int i) {
    volatile int* vl = lab;
    int r = i;
    int e = vl[r] & IDXMASK;
    while (e != r) {
        int e2 = vl[e] & IDXMASK;
        if (e2 != e) lab[r] = e2;
        r = e; e = e2;
    }
    return r;
}

__device__ __forceinline__ void uniteL(int* lab, int a, int b) {
    int ra = findRootL(lab, a), rb = findRootL(lab, b);
    while (ra != rb) {
        if (ra < rb) { int t = ra; ra = rb; rb = t; }
        int prev = atomicCAS(&lab[ra], ra, rb);
        if (prev == ra) return;
        ra = findRootL(lab, prev & IDXMASK);
        rb = findRootL(lab, rb);
    }
}

// index (within row) of the run containing bit b of this word; requires fg@b.
__device__ __forceinline__ int runIndexW(u64 starts, int b) {
    u64 below = (2ULL << b) - 1ULL;  // b=63 wraps to ~0ULL
    return (int)__popcll(starts & below) - 1;
}

__global__ void k_zero(double* __restrict__ part) {
    part[blockIdx.x * blockDim.x + threadIdx.x] = 0.0;
}

__device__ __forceinline__ float packf(float mag, bool fl) {
    return __uint_as_float(__float_as_uint(mag) | (fl ? 0x80000000u : 0u));
}

// Per-phase: one lane's 16-px chunk. Run sums (sign = mistake flag) + starts.
__device__ __forceinline__ void phaseRuns(int lane, int mask, int maskMist,
                                          const float* lossv,
                                          long rbase, float* __restrict__ runsum,
                                          int* __restrict__ rcOut, int R,
                                          int& startsOut, int& exclOut) {
    int prevm = __shfl_up(mask, 1, 64);
    int carry = (lane == 0) ? 0 : ((prevm >> 15) & 1);
    int starts = mask & ~((mask << 1) | carry) & 0xFFFF;
    int cnt = __popc(starts);
    int incl = cnt;
    #pragma unroll
    for (int d = 1; d < 64; d <<= 1) {
        int u = __shfl_up(incl, d, 64);
        if (lane >= d) incl += u;
    }
    int excl = incl - cnt;
    // serial in-lane pass: complete runs write directly (sign = mistake bit)
    float cur = 0.0f, headmag = 0.0f;
    bool curf = false, headf = false;
    bool begun = false, prevfg = (carry != 0), hasHead = false;
    int scount = 0;
    #pragma unroll
    for (int k = 0; k < 16; ++k) {
        bool fg = (mask >> k) & 1;
        bool mk = (maskMist >> k) & 1;
        if (fg) {
            if ((starts >> k) & 1) { cur = lossv[k]; curf = mk; begun = true; ++scount; }
            else { cur += lossv[k]; curf |= mk; }
        } else {
            if (prevfg) {
                if (begun) runsum[rbase + excl + scount - 1] = packf(cur, curf);
                else { hasHead = true; headmag = cur; headf = curf; }
            }
        }
        prevfg = fg;
    }
    // segmented sum scan for cross-lane runs (sign bit ORs along with the add)
    float sv = prevfg ? packf(cur, curf) : 0.0f;
    int fl = (starts != 0);
    #pragma unroll
    for (int d = 1; d < 64; d <<= 1) {
        float u = __shfl_up(sv, d, 64);
        int uf = __shfl_up(fl, d, 64);
        if (lane >= d) {
            if (!fl) {
                unsigned sg = (__float_as_uint(sv) | __float_as_uint(u)) & 0x80000000u;
                float mag = fabsf(sv) + fabsf(u);
                sv = __uint_as_float(__float_as_uint(mag) | sg);
            }
            fl |= uf;
        }
    }
    float svprev = __shfl_up(sv, 1, 64);
    if (hasHead) {
        unsigned sg = (__float_as_uint(svprev) & 0x80000000u) | (headf ? 0x80000000u : 0u);
        float mag = fabsf(svprev) + headmag;
        runsum[rbase + excl - 1] = __uint_as_float(__float_as_uint(mag) | sg);
    }
    if (lane == 63) {
        if (prevfg) runsum[rbase + incl - 1] = sv;  // keeps packed sign
        rcOut[R] = incl;
    }
    startsOut = starts;
    exclOut = excl;
}

// Wave-per-row, lane-chunk layout: lane l owns pixels [16l, 16l+16).
__global__ void k_maskloss(const float* __restrict__ preds, const float* __restrict__ targets,
                           long gbase, int nrows,
                           u64* __restrict__ fT, u64* __restrict__ fP,
                           u64* __restrict__ sT, u64* __restrict__ sP,
                           int* __restrict__ prT, int* __restrict__ prP,
                           int* __restrict__ rcT, int* __restrict__ rcP,
                           float* __restrict__ runsumT, float* __restrict__ runsumP,
                           double* __restrict__ part) {
    __shared__ double sh[4];
    int wid = threadIdx.x >> 6, lane = threadIdx.x & 63;
    double lsum = 0.0;
    for (int R = blockIdx.x * 4 + wid; R < nrows; R += gridDim.x * 4) {
        long pixbase = (long)R * WW;
        long rbase = (long)R * RPR;
        const float4* p4 = (const float4*)(preds + gbase + pixbase);
        const float4* t4 = (const float4*)(targets + gbase + pixbase);
        float lossv[16];
        int maskT = 0, maskP = 0;
        float rowsum = 0.0f;
        #pragma unroll
        for (int j = 0; j < 4; ++j) {
            float4 pv = p4[lane * 4 + j];
            float4 tv = t4[lane * 4 + j];
            float pp[4] = {pv.x, pv.y, pv.z, pv.w};
            float tt[4] = {tv.x, tv.y, tv.z, tv.w};
            #pragma unroll
            for (int q = 0; q < 4; ++q) {
                int k = j * 4 + q;
                float p = pp[q], t = tt[q];
                float loss = fmaxf(p, 0.0f) - p * t + __logf(1.0f + __expf(-fabsf(p)));
                lossv[k] = loss;
                rowsum += loss;
                maskT |= ((int)(t > 0.0f)) << k;
                maskP |= ((int)(p > 0.5f)) << k;
            }
        }
        lsum += (double)rowsum;

        int mistT = maskT & ~maskP;  // target-fg not covered by pred-fg
        int mistP = maskP & ~maskT;  // pred-fg not covered by target-fg
        int stT_, exT, stP_, exP;
        phaseRuns(lane, maskT, mistT, lossv, rbase, runsumT, rcT, R, stT_, exT);
        phaseRuns(lane, maskP, mistP, lossv, rbase, runsumP, rcP, R, stP_, exP);

        // pack word-format outputs: lanes 0..15 -> T words, 16..31 -> P words
        int subid = lane & 15;
        int srcl = subid * 4;
        u64 fw = 0, sw = 0;
        #pragma unroll
        for (int j = 0; j < 4; ++j) {
            int mT = __shfl(maskT, srcl + j, 64);
            int mP = __shfl(maskP, srcl + j, 64);
            int aT = __shfl(stT_, srcl + j, 64);
            int aP = __shfl(stP_, srcl + j, 64);
            u64 m = (u64)(unsigned)((lane < 16) ? mT : mP);
            u64 a = (u64)(unsigned)((lane < 16) ? aT : aP);
            fw |= m << (16 * j);
            sw |= a << (16 * j);
        }
        int eT = __shfl(exT, srcl, 64);
        int eP = __shfl(exP, srcl, 64);
        int wi = R * WPR + subid;
        if (lane < 16) { fT[wi] = fw; sT[wi] = sw; prT[wi] = eT; }
        else if (lane < 32) { fP[wi] = fw; sP[wi] = sw; prP[wi] = eP; }
    }
    lsum *= 0.5;
    #pragma unroll
    for (int off = 32; off > 0; off >>= 1) lsum += __shfl_down(lsum, off, 64);
    if (lane == 0) sh[wid] = lsum;
    __syncthreads();
    if (threadIdx.x == 0) part[blockIdx.x] += sh[0] + sh[1] + sh[2] + sh[3];
}

// One block per (image, strip, phase): intra-strip CCL in 64KB LDS.
// Mistake flags come from runsum sign; OR'd onto static roots in pass A.
__global__ __launch_bounds__(NTHR_S) void
k_strip(const u64* __restrict__ fT, const u64* __restrict__ fP,
        const u64* __restrict__ sT, const u64* __restrict__ sP,
        const int* __restrict__ prT, const int* __restrict__ prP,
        const int* __restrict__ rcT, const int* __restrict__ rcP,
        const float* __restrict__ runsumT, const float* __restrict__ runsumP,
        int* __restrict__ parentT, int* __restrict__ parentP) {
    __shared__ int lab[SLOTS];
    __shared__ int rcL[SROWS];
    int bid = blockIdx.x;
    int ph = bid & 1; bid >>= 1;
    int strip = bid & (STRIPS - 1);
    int img = bid >> 5;  // STRIPS = 32
    const u64* f = ph ? fP : fT;
    const u64* s = ph ? sP : sT;
    const int* pr = ph ? prP : prT;
    const int* rc = ph ? rcP : rcT;
    const float* runsum = ph ? runsumP : runsumT;
    int* parent = ph ? parentP : parentT;
    const int row0 = img * HH + strip * SROWS;

    if (threadIdx.x < SROWS) rcL[threadIdx.x] = rc[row0 + threadIdx.x];
    __syncthreads();

    // init used slots only
    for (int i = threadIdx.x; i < SLOTS; i += NTHR_S)
        if ((i & (RPR - 1)) < rcL[i >> 9]) lab[i] = i;
    __syncthreads();

    // intra-strip vertical unites, 2-way sub-word split
    for (int task = threadIdx.x; task < (SROWS - 1) * WPR * 2; task += NTHR_S) {
        int j = task & 1, w = (task >> 1) & 15, r = task >> 5;
        int w0 = (row0 + r) * WPR + w, w1 = w0 + WPR;
        u64 o = f[w0] & f[w1];
        if (!o) continue;
        u64 s0 = s[w0], s1 = s[w1];
        int b0 = r * RPR + pr[w0], b1 = (r + 1) * RPR + pr[w1];
        u64 os = o & ~(o << 1);
        int k = 0;
        while (os) {
            int b = __builtin_ctzll(os);
            os &= os - 1;
            if ((k++ & 1) == j)
                uniteL(lab, b0 + runIndexW(s0, b), b1 + runIndexW(s1, b));
        }
    }
    __syncthreads();

    // pass A: compress non-roots (tree is static now) + OR mistake flags onto
    // roots. Halving never writes roots; flags land only on true roots -> safe.
    const int gb = row0 * RPR;
    for (int i = threadIdx.x; i < SLOTS; i += NTHR_S) {
        if ((i & (RPR - 1)) >= rcL[i >> 9]) continue;
        int e = lab[i];
        int rt = e & IDXMASK;
        if (rt != i) {
            rt = findRootL(lab, i);
            parent[gb + i] = gb + rt;
        }
        if (__float_as_uint(runsum[gb + i]) >> 31) {
            if (!(((volatile int*)lab)[rt] & FLAGBIT)) atomicOr(&lab[rt], FLAGBIT);
        }
    }
    __syncthreads();

    // pass B: root entries carry their settled flag
    for (int i = threadIdx.x; i < SLOTS; i += NTHR_S) {
        if ((i & (RPR - 1)) >= rcL[i >> 9]) continue;
        int e = lab[i];
        if ((e & IDXMASK) == i) parent[gb + i] = (gb + i) | (e & FLAGBIT);
    }
}

// Global flag-carrying unions across the 31 strip seams per image.
__global__ void k_bound(const u64* __restrict__ fT, const u64* __restrict__ fP,
                        const u64* __restrict__ sT, const u64* __restrict__ sP,
                        const int* __restrict__ prT, const int* __restrict__ prP,
                        int* __restrict__ parentT, int* __restrict__ parentP, int nb) {
    int tasks = nb * (STRIPS - 1) * WPR * 2;
    int stride = gridDim.x * blockDim.x;
    for (int id = blockIdx.x * blockDim.x + threadIdx.x; id < tasks; id += stride) {
        int ph = id & 1;
        int t = id >> 1;
        int w = t & 15; t >>= 4;
        int bnd = t % (STRIPS - 1);
        int img = t / (STRIPS - 1);
        int R = img * HH + bnd * SROWS + (SROWS - 1);  // last row of strip bnd
        const u64* f = ph ? fP : fT;
        const u64* s = ph ? sP : sT;
        const int* pr = ph ? prP : prT;
        int* parent = ph ? parentP : parentT;
        int w0 = R * WPR + w, w1 = w0 + WPR;
        u64 o = f[w0] & f[w1];
        if (!o) continue;
        u64 s0 = s[w0], s1 = s[w1];
        int b0 = R * RPR + pr[w0], b1 = (R + 1) * RPR + pr[w1];
        u64 os = o & ~(o << 1);
        while (os) {
            int b = __builtin_ctzll(os);
            os &= os - 1;
            uniteGF(parent, b0 + runIndexW(s0, b), b1 + runIndexW(s1, b));
        }
    }
}

// Per used run slot (x4 vectorized): root flag ? 0.25*|runsum| -> partials.
__global__ void k_accumrun(const int* __restrict__ rcT, const int* __restrict__ rcP,
                           int* __restrict__ parentT, int* __restrict__ parentP,
                           const float* __restrict__ runsumT, const float* __restrict__ runsumP,
                           double* __restrict__ part, int nslots) {
    int stride = gridDim.x * blockDim.x;
    double local = 0.0;
    int ngroups = nslots >> 2;  // 4 slots per group, always within one row
    for (int g = blockIdx.x * blockDim.x + threadIdx.x; g < ngroups; g += stride) {
        int base = g << 2;
        int row = base >> 9, k = base & (RPR - 1);
        int nT = rcT[row] - k, nP = rcP[row] - k;
        if (nT > 0) {
            int4 e4 = *(const int4*)&parentT[base];
            float4 r4 = *(const float4*)&runsumT[base];
            int ee[4] = {e4.x, e4.y, e4.z, e4.w};
            float rr[4] = {r4.x, r4.y, r4.z, r4.w};
            int n = nT < 4 ? nT : 4;
            for (int j = 0; j < n; ++j) {
                int e = ee[j];
                int r = e & IDXMASK;
                int fl;
                if (r == base + j) fl = e & FLAGBIT;
                else { r = findRootH(parentT, r); fl = parentT[r] & FLAGBIT; }
                if (fl) local += 0.25 * (double)fabsf(rr[j]);
            }
        }
        if (nP > 0) {
            int4 e4 = *(const int4*)&parentP[base];
            float4 r4 = *(const float4*)&runsumP[base];
            int ee[4] = {e4.x, e4.y, e4.z, e4.w};
            float rr[4] = {r4.x, r4.y, r4.z, r4.w};
            int n = nP < 4 ? nP : 4;
            for (int j = 0; j < n; ++j) {
                int e = ee[j];
                int r = e & IDXMASK;
                int fl;
                if (r == base + j) fl = e & FLAGBIT;
                else { r = findRootH(parentP, r); fl = parentP[r] & FLAGBIT; }
                if (fl) local += 0.25 * (double)fabsf(rr[j]);
            }
        }
    }
    #pragma unroll
    for (int off = 32; off > 0; off >>= 1) local += __shfl_down(local, off, 64);
    __shared__ double sh[NTHR / 64];
    int lane = threadIdx.x & 63, wid = threadIdx.x >> 6;
    if (lane == 0) sh[wid] = local;
    __syncthreads();
    if (threadIdx.x == 0) {
        double tot = 0.0;
        #pragma unroll
        for (int w = 0; w < NTHR / 64; ++w) tot += sh[w];
        part[blockIdx.x] += tot;
    }
}

__global__ void k_final(const double* __restrict__ part, float* __restrict__ out, double inv_n) {
    double v = 0.0;
    for (int i = threadIdx.x; i < NPART; i += blockDim.x) v += part[i];
    #pragma unroll
    for (int off = 32; off > 0; off >>= 1) v += __shfl_down(v, off, 64);
    __shared__ double sh[NTHR / 64];
    int lane = threadIdx.x & 63, wid = threadIdx.x >> 6;
    if (lane == 0) sh[wid] = v;
    __syncthreads();
    if (threadIdx.x == 0) {
        double tot = 0.0;
        #pragma unroll
        for (int w = 0; w < NTHR / 64; ++w) tot += sh[w];
        out[0] = (float)(tot * inv_n);
    }
}

extern "C" void kernel_launch(void* const* d_in, const int* in_sizes, int n_in,
                              void* d_out, int out_size, void* d_ws, size_t ws_size,
                              hipStream_t stream) {
    const float* preds = (const float*)d_in[0];
    const float* targets = (const float*)d_in[1];
    float* out = (float*)d_out;

    // ws: part | fT fP sT sP (u64) | prT prP rcT rcP parentT parentP (int)
    //    | runsumT runsumP (f32)           (chunked by image)
    double* part = (double*)d_ws;
    char* base = (char*)d_ws + NPART * sizeof(double);
    size_t avail = (ws_size > NPART * sizeof(double)) ? ws_size - NPART * sizeof(double) : 0;
    const size_t wpi = (size_t)HH * WPR;       // 16384 words per image
    const size_t runs_pi = (size_t)HH * RPR;   // 524288 run slots per image
    const size_t per_img = 4 * wpi * sizeof(u64) + 2 * wpi * sizeof(int)
                         + 2 * HH * sizeof(int) + 2 * runs_pi * sizeof(int)
                         + 2 * runs_pi * sizeof(float);  // ~9.1 MB
    int chunk = (int)(avail / per_img);
    if (chunk < 1) chunk = 1;
    if (chunk > NB_TOTAL) chunk = NB_TOTAL;

    u64* fT = (u64*)base;
    u64* fP = fT + (size_t)chunk * wpi;
    u64* sT = fP + (size_t)chunk * wpi;
    u64* sP = sT + (size_t)chunk * wpi;
    int* prT = (int*)(sP + (size_t)chunk * wpi);
    int* prP = prT + (size_t)chunk * wpi;
    int* rcT = prP + (size_t)chunk * wpi;
    int* rcP = rcT + (size_t)chunk * HH;
    int* parentT = rcP + (size_t)chunk * HH;
    int* parentP = parentT + (size_t)chunk * runs_pi;
    float* runsumT = (float*)(parentP + (size_t)chunk * runs_pi);
    float* runsumP = runsumT + (size_t)chunk * runs_pi;

    k_zero<<<NPART / NTHR, NTHR, 0, stream>>>(part);

    for (int b0 = 0; b0 < NB_TOTAL; b0 += chunk) {
        int nb = (b0 + chunk <= NB_TOTAL) ? chunk : (NB_TOTAL - b0);
        long gbase = (long)b0 * IMGPIX;
        int nrows = nb * HH;
        int nslots = (int)(nb * runs_pi);

        k_maskloss<<<NBLK, NTHR, 0, stream>>>(preds, targets, gbase, nrows,
                                              fT, fP, sT, sP, prT, prP, rcT, rcP,
                                              runsumT, runsumP, part);
        k_strip<<<nb * STRIPS * 2, NTHR_S, 0, stream>>>(fT, fP, sT, sP, prT, prP,
                                                        rcT, rcP, runsumT, runsumP,
                                                        parentT, parentP);
        k_bound<<<512, NTHR, 0, stream>>>(fT, fP, sT, sP, prT, prP, parentT, parentP, nb);
        k_accumrun<<<NBLK, NTHR, 0, stream>>>(rcT, rcP, parentT, parentP,
                                              runsumT, runsumP, part, nslots);
    }

    double inv_n = 1.0 / ((double)NB_TOTAL * (double)IMGPIX);
    k_final<<<1, NTHR, 0, stream>>>(part, out, inv_n);
}

// Round 14
// 243.113 us; speedup vs baseline: 1.2617x; 1.0027x over previous
//
#include <hip/hip_runtime.h>
#include <math.h>

// SuperVoxel critical-component loss on MI355X.
// mean( (0.5 + 0.25*neg + 0.25*pos) * bce_loss )
// Run-based two-level CCL with path-halving union-find and PER-RUN loss sums.
//  k_maskloss: COALESCED word-order dword loads; loss staged through a
//              wave-private XOR-swizzled LDS tile into lane-chunk order
//              (16 px/lane); run sums via serial in-lane loop + ONE segmented
//              scan; run's "contains mistake" bit packed into runsum SIGN;
//              ballots emit word-format fg masks directly.
//  k_strip:    32-row strips, intra-strip unions in 64KB LDS; compress pass A
//              ORs sign-bit mistake flags onto static roots.
//  k_bound:    global flag-carrying unions on 31 strip seams per image.
//  k_accumrun: per used run slot (x4 vectorized): root flag ? 0.25*|runsum|.

#define HH 1024
#define WW 1024
#define IMGPIX (HH * WW)
#define NB_TOTAL 16
#define FLAGBIT 0x40000000
#define IDXMASK 0x3FFFFFFF
#define NBLK 2048
#define NPART 2048
#define NTHR 256
#define WPR 16               // u64 mask words per row
#define RPR 512              // run slots per row (hard worst case)
#define SROWS 32             // rows per strip
#define STRIPS (HH / SROWS)  // 32 strips per image
#define SLOTS (SROWS * RPR)  // 16384 slots per strip (64KB LDS)
#define NTHR_S 1024
#define STAGEF 1280          // floats per wave stage tile (20 floats / 16 px)

typedef unsigned long long u64;

// ---------- global union-find, path-halving, flag-aware ----------
__device__ __forceinline__ int findRootH(int* p, int i) {
    volatile int* vp = p;
    int r = i;
    int e = vp[r] & IDXMASK;
    while (e != r) {
        int e2 = vp[e] & IDXMASK;
        if (e2 != e) p[r] = e2;  // shortcut: only non-roots written (no flags there)
        r = e; e = e2;
    }
    return r;
}

__device__ __forceinline__ void flagProp(int* p, int x) {
    while (true) {
        int r = findRootH(p, x);
        int old = atomicOr(&p[r], FLAGBIT);
        if ((old & IDXMASK) == r) return;  // was still a root
        x = old & IDXMASK;
    }
}

__device__ __forceinline__ void uniteGF(int* p, int a, int b) {
    int ra = findRootH(p, a), rb = findRootH(p, b);
    while (ra != rb) {
        if (ra < rb) { int t = ra; ra = rb; rb = t; }  // hook larger under smaller
        int e = p[ra];
        if ((e & IDXMASK) != ra) { ra = findRootH(p, e & IDXMASK); continue; }
        int prev = atomicCAS(&p[ra], e, rb);
        if (prev == e) {
            if (e & FLAGBIT) flagProp(p, rb);
            return;
        }
        ra = findRootH(p, prev & IDXMASK);
        rb = findRootH(p, rb);
    }
}

// ---------- LDS union-find, path-halving ----------
__device__ __forceinline__ int findRootL(int* lab, int i) {
    volatile int* vl = lab;
    int r = i;
    int e = vl[r] & IDXMASK;
    while (e != r) {
        int e2 = vl[e] & IDXMASK;
        if (e2 != e) lab[r] = e2;
        r = e; e = e2;
    }
    return r;
}

__device__ __forceinline__ void uniteL(int* lab, int a, int b) {
    int ra = findRootL(lab, a), rb = findRootL(lab, b);
    while (ra != rb) {
        if (ra < rb) { int t = ra; ra = rb; rb = t; }
        int prev = atomicCAS(&lab[ra], ra, rb);
        if (prev == ra) return;
        ra = findRootL(lab, prev & IDXMASK);
        rb = findRootL(lab, rb);
    }
}

// index (within row) of the run containing bit b of this word; requires fg@b.
__device__ __forceinline__ int runIndexW(u64 starts, int b) {
    u64 below = (2ULL << b) - 1ULL;  // b=63 wraps to ~0ULL
    return (int)__popcll(starts & below) - 1;
}

__global__ void k_zero(double* __restrict__ part) {
    part[blockIdx.x * blockDim.x + threadIdx.x] = 0.0;
}

__device__ __forceinline__ float packf(float mag, bool fl) {
    return __uint_as_float(__float_as_uint(mag) | (fl ? 0x80000000u : 0u));
}

// Per-phase: one lane's 16-px chunk. Run sums (sign = mistake flag) + starts.
__device__ __forceinline__ void phaseRuns(int lane, int mask, int maskMist,
                                          const float* lossv,
                                          long rbase, float* __restrict__ runsum,
                                          int* __restrict__ rcOut, int R,
                                          int& startsOut, int& exclOut) {
    int prevm = __shfl_up(mask, 1, 64);
    int carry = (lane == 0) ? 0 : ((prevm >> 15) & 1);
    int starts = mask & ~((mask << 1) | carry) & 0xFFFF;
    int cnt = __popc(starts);
    int incl = cnt;
    #pragma unroll
    for (int d = 1; d < 64; d <<= 1) {
        int u = __shfl_up(incl, d, 64);
        if (lane >= d) incl += u;
    }
    int excl = incl - cnt;
    // serial in-lane pass: complete runs write directly (sign = mistake bit)
    float cur = 0.0f, headmag = 0.0f;
    bool curf = false, headf = false;
    bool begun = false, prevfg = (carry != 0), hasHead = false;
    int scount = 0;
    #pragma unroll
    for (int k = 0; k < 16; ++k) {
        bool fg = (mask >> k) & 1;
        bool mk = (maskMist >> k) & 1;
        if (fg) {
            if ((starts >> k) & 1) { cur = lossv[k]; curf = mk; begun = true; ++scount; }
            else { cur += lossv[k]; curf |= mk; }
        } else {
            if (prevfg) {
                if (begun) runsum[rbase + excl + scount - 1] = packf(cur, curf);
                else { hasHead = true; headmag = cur; headf = curf; }
            }
        }
        prevfg = fg;
    }
    // segmented sum scan for cross-lane runs (sign bit ORs along with the add)
    float sv = prevfg ? packf(cur, curf) : 0.0f;
    int fl = (starts != 0);
    #pragma unroll
    for (int d = 1; d < 64; d <<= 1) {
        float u = __shfl_up(sv, d, 64);
        int uf = __shfl_up(fl, d, 64);
        if (lane >= d) {
            if (!fl) {
                unsigned sg = (__float_as_uint(sv) | __float_as_uint(u)) & 0x80000000u;
                float mag = fabsf(sv) + fabsf(u);
                sv = __uint_as_float(__float_as_uint(mag) | sg);
            }
            fl |= uf;
        }
    }
    float svprev = __shfl_up(sv, 1, 64);
    if (hasHead) {
        unsigned sg = (__float_as_uint(svprev) & 0x80000000u) | (headf ? 0x80000000u : 0u);
        float mag = fabsf(svprev) + headmag;
        runsum[rbase + excl - 1] = __uint_as_float(__float_as_uint(mag) | sg);
    }
    if (lane == 63) {
        if (prevfg) runsum[rbase + incl - 1] = sv;  // keeps packed sign
        rcOut[R] = incl;
    }
    startsOut = starts;
    exclOut = excl;
}

// Wave-per-row. Coalesced word-order loads; loss -> wave-private swizzled LDS
// tile -> lane-chunk registers. Ballots give word masks (fT/fP) for free.
__global__ void k_maskloss(const float* __restrict__ preds, const float* __restrict__ targets,
                           long gbase, int nrows,
                           u64* __restrict__ fT, u64* __restrict__ fP,
                           u64* __restrict__ sT, u64* __restrict__ sP,
                           int* __restrict__ prT, int* __restrict__ prP,
                           int* __restrict__ rcT, int* __restrict__ rcP,
                           float* __restrict__ runsumT, float* __restrict__ runsumP,
                           double* __restrict__ part) {
    __shared__ float stage[4][STAGEF];  // 20KB/block -> 8 blocks/CU
    int wid = threadIdx.x >> 6, lane = threadIdx.x & 63;
    float* st = stage[wid];
    double lsum = 0.0;
    for (int R = blockIdx.x * 4 + wid; R < nrows; R += gridDim.x * 4) {
        long pixbase = (long)R * WW;
        long rbase = (long)R * RPR;
        const float* pr_ = preds + gbase + pixbase;
        const float* tg_ = targets + gbase + pixbase;
        u64 myW = 0;  // lanes 0..15: T word[lane]; lanes 16..31: P word[lane-16]
        float rowsum = 0.0f;
        #pragma unroll
        for (int w = 0; w < WPR; ++w) {
            float p = pr_[w * 64 + lane];   // coalesced dword
            float t = tg_[w * 64 + lane];
            float loss = fmaxf(p, 0.0f) - p * t + __logf(1.0f + __expf(-fabsf(p)));
            rowsum += loss;
            u64 bt = __ballot(t > 0.0f);
            u64 bp = __ballot(p > 0.5f);
            if (lane == w) myW = bt;
            if (lane == w + 16) myW = bp;
            // chunk-order swizzled store: px = w*64+lane
            int c = 4 * w + (lane >> 4);
            int ksw = ((lane >> 2) & 3) ^ ((c >> 3) & 3);
            st[20 * c + 4 * ksw + (lane & 3)] = loss;
        }
        lsum += (double)rowsum;
        // lane-chunk fg masks via 2 shuffles from ballot words
        int wsrc = lane >> 2;
        u64 wT = __shfl(myW, wsrc, 64);
        u64 wP = __shfl(myW, 16 + wsrc, 64);
        int sh16 = 16 * (lane & 3);
        int maskT = (int)((wT >> sh16) & 0xFFFFULL);
        int maskP = (int)((wP >> sh16) & 0xFFFFULL);
        // read back loss in chunk order (swizzle-inverse, b128, conflict-free)
        float lossv[16];
        #pragma unroll
        for (int k = 0; k < 4; ++k) {
            int ksw = k ^ ((lane >> 3) & 3);
            float4 v = *(const float4*)&st[20 * lane + 4 * ksw];
            lossv[4 * k + 0] = v.x; lossv[4 * k + 1] = v.y;
            lossv[4 * k + 2] = v.z; lossv[4 * k + 3] = v.w;
        }

        int mistT = maskT & ~maskP;
        int mistP = maskP & ~maskT;
        int stT_, exT, stP_, exP;
        phaseRuns(lane, maskT, mistT, lossv, rbase, runsumT, rcT, R, stT_, exT);
        phaseRuns(lane, maskP, mistP, lossv, rbase, runsumP, rcP, R, stP_, exP);

        // word-format starts/prefix outputs (fg word = myW directly)
        int subid = lane & 15;
        int srcl = subid * 4;
        u64 sw_ = 0;
        #pragma unroll
        for (int j = 0; j < 4; ++j) {
            int aT = __shfl(stT_, srcl + j, 64);
            int aP = __shfl(stP_, srcl + j, 64);
            u64 a = (u64)(unsigned)((lane < 16) ? aT : aP);
            sw_ |= a << (16 * j);
        }
        int eT = __shfl(exT, srcl, 64);
        int eP = __shfl(exP, srcl, 64);
        int wi = R * WPR + subid;
        if (lane < 16) { fT[wi] = myW; sT[wi] = sw_; prT[wi] = eT; }
        else if (lane < 32) { fP[wi] = myW; sP[wi] = sw_; prP[wi] = eP; }
    }
    lsum *= 0.5;
    #pragma unroll
    for (int off = 32; off > 0; off >>= 1) lsum += __shfl_down(lsum, off, 64);
    __syncthreads();                       // stage tiles now reusable as scratch
    double* shd = (double*)&stage[0][0];
    if (lane == 0) shd[wid] = lsum;
    __syncthreads();
    if (threadIdx.x == 0) part[blockIdx.x] += shd[0] + shd[1] + shd[2] + shd[3];
}

// One block per (image, strip, phase): intra-strip CCL in 64KB LDS.
// Mistake flags come from runsum sign; OR'd onto static roots in pass A.
__global__ __launch_bounds__(NTHR_S) void
k_strip(const u64* __restrict__ fT, const u64* __restrict__ fP,
        const u64* __restrict__ sT, const u64* __restrict__ sP,
        const int* __restrict__ prT, const int* __restrict__ prP,
        const int* __restrict__ rcT, const int* __restrict__ rcP,
        const float* __restrict__ runsumT, const float* __restrict__ runsumP,
        int* __restrict__ parentT, int* __restrict__ parentP) {
    __shared__ int lab[SLOTS];
    __shared__ int rcL[SROWS];
    int bid = blockIdx.x;
    int ph = bid & 1; bid >>= 1;
    int strip = bid & (STRIPS - 1);
    int img = bid >> 5;  // STRIPS = 32
    const u64* f = ph ? fP : fT;
    const u64* s = ph ? sP : sT;
    const int* pr = ph ? prP : prT;
    const int* rc = ph ? rcP : rcT;
    const float* runsum = ph ? runsumP : runsumT;
    int* parent = ph ? parentP : parentT;
    const int row0 = img * HH + strip * SROWS;

    if (threadIdx.x < SROWS) rcL[threadIdx.x] = rc[row0 + threadIdx.x];
    __syncthreads();

    // init used slots only
    for (int i = threadIdx.x; i < SLOTS; i += NTHR_S)
        if ((i & (RPR - 1)) < rcL[i >> 9]) lab[i] = i;
    __syncthreads();

    // intra-strip vertical unites, 2-way sub-word split
    for (int task = threadIdx.x; task < (SROWS - 1) * WPR * 2; task += NTHR_S) {
        int j = task & 1, w = (task >> 1) & 15, r = task >> 5;
        int w0 = (row0 + r) * WPR + w, w1 = w0 + WPR;
        u64 o = f[w0] & f[w1];
        if (!o) continue;
        u64 s0 = s[w0], s1 = s[w1];
        int b0 = r * RPR + pr[w0], b1 = (r + 1) * RPR + pr[w1];
        u64 os = o & ~(o << 1);
        int k = 0;
        while (os) {
            int b = __builtin_ctzll(os);
            os &= os - 1;
            if ((k++ & 1) == j)
                uniteL(lab, b0 + runIndexW(s0, b), b1 + runIndexW(s1, b));
        }
    }
    __syncthreads();

    // pass A: compress non-roots (tree static) + OR mistake flags onto roots.
    const int gb = row0 * RPR;
    for (int i = threadIdx.x; i < SLOTS; i += NTHR_S) {
        if ((i & (RPR - 1)) >= rcL[i >> 9]) continue;
        int e = lab[i];
        int rt = e & IDXMASK;
        if (rt != i) {
            rt = findRootL(lab, i);
            parent[gb + i] = gb + rt;
        }
        if (__float_as_uint(runsum[gb + i]) >> 31) {
            if (!(((volatile int*)lab)[rt] & FLAGBIT)) atomicOr(&lab[rt], FLAGBIT);
        }
    }
    __syncthreads();

    // pass B: root entries carry their settled flag
    for (int i = threadIdx.x; i < SLOTS; i += NTHR_S) {
        if ((i & (RPR - 1)) >= rcL[i >> 9]) continue;
        int e = lab[i];
        if ((e & IDXMASK) == i) parent[gb + i] = (gb + i) | (e & FLAGBIT);
    }
}

// Global flag-carrying unions across the 31 strip seams per image.
__global__ void k_bound(const u64* __restrict__ fT, const u64* __restrict__ fP,
                        const u64* __restrict__ sT, const u64* __restrict__ sP,
                        const int* __restrict__ prT, const int* __restrict__ prP,
                        int* __restrict__ parentT, int* __restrict__ parentP, int nb) {
    int tasks = nb * (STRIPS - 1) * WPR * 2;
    int stride = gridDim.x * blockDim.x;
    for (int id = blockIdx.x * blockDim.x + threadIdx.x; id < tasks; id += stride) {
        int ph = id & 1;
        int t = id >> 1;
        int w = t & 15; t >>= 4;
        int bnd = t % (STRIPS - 1);
        int img = t / (STRIPS - 1);
        int R = img * HH + bnd * SROWS + (SROWS - 1);  // last row of strip bnd
        const u64* f = ph ? fP : fT;
        const u64* s = ph ? sP : sT;
        const int* pr = ph ? prP : prT;
        int* parent = ph ? parentP : parentT;
        int w0 = R * WPR + w, w1 = w0 + WPR;
        u64 o = f[w0] & f[w1];
        if (!o) continue;
        u64 s0 = s[w0], s1 = s[w1];
        int b0 = R * RPR + pr[w0], b1 = (R + 1) * RPR + pr[w1];
        u64 os = o & ~(o << 1);
        while (os) {
            int b = __builtin_ctzll(os);
            os &= os - 1;
            uniteGF(parent, b0 + runIndexW(s0, b), b1 + runIndexW(s1, b));
        }
    }
}

// Per used run slot (x4 vectorized): root flag ? 0.25*|runsum| -> partials.
__global__ void k_accumrun(const int* __restrict__ rcT, const int* __restrict__ rcP,
                           int* __restrict__ parentT, int* __restrict__ parentP,
                           const float* __restrict__ runsumT, const float* __restrict__ runsumP,
                           double* __restrict__ part, int nslots) {
    int stride = gridDim.x * blockDim.x;
    double local = 0.0;
    int ngroups = nslots >> 2;  // 4 slots per group, always within one row
    for (int g = blockIdx.x * blockDim.x + threadIdx.x; g < ngroups; g += stride) {
        int base = g << 2;
        int row = base >> 9, k = base & (RPR - 1);
        int nT = rcT[row] - k, nP = rcP[row] - k;
        if (nT > 0) {
            int4 e4 = *(const int4*)&parentT[base];
            float4 r4 = *(const float4*)&runsumT[base];
            int ee[4] = {e4.x, e4.y, e4.z, e4.w};
            float rr[4] = {r4.x, r4.y, r4.z, r4.w};
            int n = nT < 4 ? nT : 4;
            for (int j = 0; j < n; ++j) {
                int e = ee[j];
                int r = e & IDXMASK;
                int fl;
                if (r == base + j) fl = e & FLAGBIT;
                else { r = findRootH(parentT, r); fl = parentT[r] & FLAGBIT; }
                if (fl) local += 0.25 * (double)fabsf(rr[j]);
            }
        }
        if (nP > 0) {
            int4 e4 = *(const int4*)&parentP[base];
            float4 r4 = *(const float4*)&runsumP[base];
            int ee[4] = {e4.x, e4.y, e4.z, e4.w};
            float rr[4] = {r4.x, r4.y, r4.z, r4.w};
            int n = nP < 4 ? nP : 4;
            for (int j = 0; j < n; ++j) {
                int e = ee[j];
                int r = e & IDXMASK;
                int fl;
                if (r == base + j) fl = e & FLAGBIT;
                else { r = findRootH(parentP, r); fl = parentP[r] & FLAGBIT; }
                if (fl) local += 0.25 * (double)fabsf(rr[j]);
            }
        }
    }
    #pragma unroll
    for (int off = 32; off > 0; off >>= 1) local += __shfl_down(local, off, 64);
    __shared__ double sh[NTHR / 64];
    int lane = threadIdx.x & 63, wid = threadIdx.x >> 6;
    if (lane == 0) sh[wid] = local;
    __syncthreads();
    if (threadIdx.x == 0) {
        double tot = 0.0;
        #pragma unroll
        for (int w = 0; w < NTHR / 64; ++w) tot += sh[w];
        part[blockIdx.x] += tot;
    }
}

__global__ void k_final(const double* __restrict__ part, float* __restrict__ out, double inv_n) {
    double v = 0.0;
    for (int i = threadIdx.x; i < NPART; i += blockDim.x) v += part[i];
    #pragma unroll
    for (int off = 32; off > 0; off >>= 1) v += __shfl_down(v, off, 64);
    __shared__ double sh[NTHR / 64];
    int lane = threadIdx.x & 63, wid = threadIdx.x >> 6;
    if (lane == 0) sh[wid] = v;
    __syncthreads();
    if (threadIdx.x == 0) {
        double tot = 0.0;
        #pragma unroll
        for (int w = 0; w < NTHR / 64; ++w) tot += sh[w];
        out[0] = (float)(tot * inv_n);
    }
}

extern "C" void kernel_launch(void* const* d_in, const int* in_sizes, int n_in,
                              void* d_out, int out_size, void* d_ws, size_t ws_size,
                              hipStream_t stream) {
    const float* preds = (const float*)d_in[0];
    const float* targets = (const float*)d_in[1];
    float* out = (float*)d_out;

    // ws: part | fT fP sT sP (u64) | prT prP rcT rcP parentT parentP (int)
    //    | runsumT runsumP (f32)           (chunked by image)
    double* part = (double*)d_ws;
    char* base = (char*)d_ws + NPART * sizeof(double);
    size_t avail = (ws_size > NPART * sizeof(double)) ? ws_size - NPART * sizeof(double) : 0;
    const size_t wpi = (size_t)HH * WPR;       // 16384 words per image
    const size_t runs_pi = (size_t)HH * RPR;   // 524288 run slots per image
    const size_t per_img = 4 * wpi * sizeof(u64) + 2 * wpi * sizeof(int)
                         + 2 * HH * sizeof(int) + 2 * runs_pi * sizeof(int)
                         + 2 * runs_pi * sizeof(float);  // ~9.1 MB
    int chunk = (int)(avail / per_img);
    if (chunk < 1) chunk = 1;
    if (chunk > NB_TOTAL) chunk = NB_TOTAL;

    u64* fT = (u64*)base;
    u64* fP = fT + (size_t)chunk * wpi;
    u64* sT = fP + (size_t)chunk * wpi;
    u64* sP = sT + (size_t)chunk * wpi;
    int* prT = (int*)(sP + (size_t)chunk * wpi);
    int* prP = prT + (size_t)chunk * wpi;
    int* rcT = prP + (size_t)chunk * wpi;
    int* rcP = rcT + (size_t)chunk * HH;
    int* parentT = rcP + (size_t)chunk * HH;
    int* parentP = parentT + (size_t)chunk * runs_pi;
    float* runsumT = (float*)(parentP + (size_t)chunk * runs_pi);
    float* runsumP = runsumT + (size_t)chunk * runs_pi;

    k_zero<<<NPART / NTHR, NTHR, 0, stream>>>(part);

    for (int b0 = 0; b0 < NB_TOTAL; b0 += chunk) {
        int nb = (b0 + chunk <= NB_TOTAL) ? chunk : (NB_TOTAL - b0);
        long gbase = (long)b0 * IMGPIX;
        int nrows = nb * HH;
        int nslots = (int)(nb * runs_pi);

        k_maskloss<<<NBLK, NTHR, 0, stream>>>(preds, targets, gbase, nrows,
                                              fT, fP, sT, sP, prT, prP, rcT, rcP,
                                              runsumT, runsumP, part);
        k_strip<<<nb * STRIPS * 2, NTHR_S, 0, stream>>>(fT, fP, sT, sP, prT, prP,
                                                        rcT, rcP, runsumT, runsumP,
                                                        parentT, parentP);
        k_bound<<<512, NTHR, 0, stream>>>(fT, fP, sT, sP, prT, prP, parentT, parentP, nb);
        k_accumrun<<<NBLK, NTHR, 0, stream>>>(rcT, rcP, parentT, parentP,
                                              runsumT, runsumP, part, nslots);
    }

    double inv_n = 1.0 / ((double)NB_TOTAL * (double)IMGPIX);
    k_final<<<1, NTHR, 0, stream>>>(part, out, inv_n);
}